// Round 1
// baseline (1231.657 us; speedup 1.0000x reference)
//
#include <hip/hip_runtime.h>
#include <hip/hip_bf16.h>

#define L_SEQ 200
#define DIM 128
#define NROWS (256*200)

__device__ __forceinline__ float wave_sum(float v){
  #pragma unroll
  for (int o = 32; o; o >>= 1) v += __shfl_xor(v, o);
  return v;
}
__device__ __forceinline__ float wave_max(float v){
  #pragma unroll
  for (int o = 32; o; o >>= 1) v = fmaxf(v, __shfl_xor(v, o));
  return v;
}

// seqs = item_emb[log_seqs]*sqrt(D) + pos_emb, masked where id==0
__global__ void embed_kernel(const int* __restrict__ lsq, const float* __restrict__ item,
                             const float* __restrict__ pos, float* __restrict__ seqs){
  int r = blockIdx.x, d = threadIdx.x;
  int it = lsq[r];
  float v = item[(size_t)it*DIM + d] * 11.313708498984761f + pos[(r % L_SEQ)*DIM + d];
  seqs[(size_t)r*DIM + d] = it ? v : 0.f;
}

// per-row layernorm, one wave per row (lane handles dims 2*lane, 2*lane+1)
__global__ __launch_bounds__(256) void ln_kernel(const float* __restrict__ in, float* __restrict__ out,
                                                 const float* __restrict__ s, const float* __restrict__ b){
  int wave = threadIdx.x >> 6, lane = threadIdx.x & 63;
  size_t r = (size_t)blockIdx.x*4 + wave;
  float2 v = ((const float2*)(in + r*DIM))[lane];
  float mu = wave_sum(v.x + v.y) * (1.f/DIM);
  float dx = v.x - mu, dy = v.y - mu;
  float var = wave_sum(dx*dx + dy*dy) * (1.f/DIM);
  float inv = 1.f / sqrtf(var + 1e-8f);
  float2 sc = ((const float2*)s)[lane];
  float2 bc = ((const float2*)b)[lane];
  float2 o;
  o.x = dx*inv*sc.x + bc.x;
  o.y = dy*inv*sc.y + bc.y;
  ((float2*)(out + r*DIM))[lane] = o;
}

// C[M x Ncols] = A[M x K=128] @ W[Ncols x 128]^T + bias (+res) (relu) (*rowmask)
// 32x32 tile, 256 threads (16x16), 2x2 outputs per thread.
template<int RELU, int RES, int MASK>
__global__ __launch_bounds__(256) void gemm_kernel(
    const float* __restrict__ A, int lda,
    const float* __restrict__ W, const float* __restrict__ bias,
    float* __restrict__ C, int ldc,
    const float* __restrict__ res,
    const int* __restrict__ lsq){
  __shared__ float As[32][132];
  __shared__ float Bs[32][132];
  int row0 = blockIdx.y * 32, col0 = blockIdx.x * 32;
  int t = threadIdx.x;
  #pragma unroll
  for (int i = 0; i < 16; ++i) {
    int idx = t + i*256;
    int rr = idx >> 7, cc = idx & 127;
    As[rr][cc] = A[(size_t)(row0 + rr)*lda + cc];
    Bs[rr][cc] = W[(size_t)(col0 + rr)*128 + cc];
  }
  __syncthreads();
  int tx = t & 15, ty = t >> 4;
  float acc00 = 0.f, acc01 = 0.f, acc10 = 0.f, acc11 = 0.f;
  #pragma unroll
  for (int k4 = 0; k4 < 32; ++k4) {
    float4 a0 = *(const float4*)&As[ty][k4*4];
    float4 a1 = *(const float4*)&As[ty+16][k4*4];
    float4 b0 = *(const float4*)&Bs[tx][k4*4];
    float4 b1 = *(const float4*)&Bs[tx+16][k4*4];
    acc00 += a0.x*b0.x + a0.y*b0.y + a0.z*b0.z + a0.w*b0.w;
    acc01 += a0.x*b1.x + a0.y*b1.y + a0.z*b1.z + a0.w*b1.w;
    acc10 += a1.x*b0.x + a1.y*b0.y + a1.z*b0.z + a1.w*b0.w;
    acc11 += a1.x*b1.x + a1.y*b1.y + a1.z*b1.z + a1.w*b1.w;
  }
  float accs[2][2] = {{acc00, acc01}, {acc10, acc11}};
  #pragma unroll
  for (int i = 0; i < 2; ++i) {
    int rr = row0 + ty + 16*i;
    #pragma unroll
    for (int j = 0; j < 2; ++j) {
      int cc = col0 + tx + 16*j;
      float v = accs[i][j] + bias[cc];
      if (RELU) v = fmaxf(v, 0.f);
      if (RES)  v += res[(size_t)rr*DIM + cc];
      if (MASK) { if (lsq[rr] == 0) v = 0.f; }
      C[(size_t)rr*ldc + cc] = v;
    }
  }
}

// causal MHA for one (batch, head). qkv layout: [row][384] = Q(128)|K(128)|V(128),
// head h uses cols h*64..h*64+63 of each. Output written over the Q slot.
__global__ __launch_bounds__(256) void attn_kernel(float* qkv){
  __shared__ float Ks[L_SEQ][65];
  __shared__ float Vs[L_SEQ][65];
  __shared__ float Pw[4][L_SEQ];
  __shared__ float Qr[4][64];
  int b = blockIdx.x >> 1, h = blockIdx.x & 1;
  float* base = qkv + (size_t)b*L_SEQ*384 + h*64;
  int t = threadIdx.x;
  for (int idx = t; idx < L_SEQ*64; idx += 256) {
    int l = idx >> 6, d = idx & 63;
    Ks[l][d] = base[(size_t)l*384 + 128 + d];
    Vs[l][d] = base[(size_t)l*384 + 256 + d];
  }
  __syncthreads();
  int wave = t >> 6, lane = t & 63;
  for (int q = wave; q < L_SEQ; q += 4) {
    Qr[wave][lane] = base[(size_t)q*384 + lane];
    __syncthreads();
    float sc[4];
    #pragma unroll
    for (int j = 0; j < 4; ++j) {
      int k = lane + 64*j;
      float s = -3.0e38f;
      if (k <= q) {
        s = 0.f;
        #pragma unroll
        for (int d = 0; d < 64; ++d) s += Qr[wave][d] * Ks[k][d];
        s *= 0.125f;
      }
      sc[j] = s;
    }
    float m = wave_max(fmaxf(fmaxf(sc[0], sc[1]), fmaxf(sc[2], sc[3])));
    float e[4], sum = 0.f;
    #pragma unroll
    for (int j = 0; j < 4; ++j) { e[j] = expf(sc[j] - m); sum += e[j]; }
    sum = wave_sum(sum);
    float inv = 1.f / sum;
    #pragma unroll
    for (int j = 0; j < 4; ++j) {
      int k = lane + 64*j;
      if (k < L_SEQ) Pw[wave][k] = e[j] * inv;
    }
    __syncthreads();
    float acc = 0.f;
    for (int k = 0; k <= q; ++k) acc += Pw[wave][k] * Vs[k][lane];
    base[(size_t)q*384 + lane] = acc;   // overwrite Q slot: Q fully consumed for this q
  }
}

// feats = LN(seqs); neighbor softmax-aggregate; out = feats + LN(agg+qn)
__global__ __launch_bounds__(256) void final_kernel(
    const float* __restrict__ seqs, const int* __restrict__ lsq, const int* __restrict__ nbr,
    const float* __restrict__ item, const float* __restrict__ user,
    const float* __restrict__ ls, const float* __restrict__ lb,
    const float* __restrict__ is_, const float* __restrict__ ib,
    float* __restrict__ out){
  int wave = threadIdx.x >> 6, lane = threadIdx.x & 63;
  size_t r = (size_t)blockIdx.x*4 + wave;
  float2 v = ((const float2*)(seqs + r*DIM))[lane];
  float mu = wave_sum(v.x + v.y) * (1.f/DIM);
  float dx = v.x - mu, dy = v.y - mu;
  float var = wave_sum(dx*dx + dy*dy) * (1.f/DIM);
  float inv = 1.f / sqrtf(var + 1e-8f);
  float2 lsc = ((const float2*)ls)[lane], lbc = ((const float2*)lb)[lane];
  float fx = dx*inv*lsc.x + lbc.x;
  float fy = dy*inv*lsc.y + lbc.y;

  int it = lsq[r];
  float2 qn = ((const float2*)(item + (size_t)it*DIM))[lane];
  float2 kn[10]; float scn[10];
  #pragma unroll
  for (int n = 0; n < 10; ++n) {
    int idx = nbr[r*10 + n];
    kn[n] = ((const float2*)(user + (size_t)idx*DIM))[lane];
    float p = wave_sum(qn.x*kn[n].x + qn.y*kn[n].y);
    scn[n] = idx ? p * 0.08838834764831845f : -1.0e9f;
  }
  float m = scn[0];
  #pragma unroll
  for (int n = 1; n < 10; ++n) m = fmaxf(m, scn[n]);
  float w[10], sum = 0.f;
  #pragma unroll
  for (int n = 0; n < 10; ++n) { w[n] = expf(scn[n] - m); sum += w[n]; }
  float invs = 1.f / sum;
  float ax = 0.f, ay = 0.f;
  #pragma unroll
  for (int n = 0; n < 10; ++n) { ax += w[n]*kn[n].x; ay += w[n]*kn[n].y; }
  ax = ax*invs + qn.x;
  ay = ay*invs + qn.y;
  float mu2 = wave_sum(ax + ay) * (1.f/DIM);
  float dx2 = ax - mu2, dy2 = ay - mu2;
  float var2 = wave_sum(dx2*dx2 + dy2*dy2) * (1.f/DIM);
  float inv2 = 1.f / sqrtf(var2 + 1e-8f);
  float2 isc = ((const float2*)is_)[lane], ibc = ((const float2*)ib)[lane];
  float2 o;
  o.x = fx + dx2*inv2*isc.x + ibc.x;
  o.y = fy + dy2*inv2*isc.y + ibc.y;
  ((float2*)(out + r*DIM))[lane] = o;
}

extern "C" void kernel_launch(void* const* d_in, const int* in_sizes, int n_in,
                              void* d_out, int out_size, void* d_ws, size_t ws_size,
                              hipStream_t stream) {
  const int*   lsq    = (const int*)d_in[0];
  const int*   nbr    = (const int*)d_in[1];
  const float* item   = (const float*)d_in[2];
  const float* user   = (const float*)d_in[3];
  const float* pos    = (const float*)d_in[4];
  const float* attn_s = (const float*)d_in[5];
  const float* attn_b = (const float*)d_in[6];
  const float* Wqkv   = (const float*)d_in[7];
  const float* bqkv   = (const float*)d_in[8];
  const float* Wo     = (const float*)d_in[9];
  const float* bo     = (const float*)d_in[10];
  const float* ffn_s  = (const float*)d_in[11];
  const float* ffn_b  = (const float*)d_in[12];
  const float* W1     = (const float*)d_in[13];
  const float* b1     = (const float*)d_in[14];
  const float* W2     = (const float*)d_in[15];
  const float* b2     = (const float*)d_in[16];
  const float* last_s = (const float*)d_in[17];
  const float* last_b = (const float*)d_in[18];
  const float* iui_s  = (const float*)d_in[19];
  const float* iui_b  = (const float*)d_in[20];
  float* out = (float*)d_out;

  const int N = NROWS;  // 51200 rows
  float* seqs = (float*)d_ws;                   // N x 128
  float* lnq  = seqs + (size_t)N*DIM;           // N x 128
  float* qkv  = lnq  + (size_t)N*DIM;           // N x 384

  embed_kernel<<<N, DIM, 0, stream>>>(lsq, item, pos, seqs);

  for (int i = 0; i < 2; ++i) {
    ln_kernel<<<N/4, 256, 0, stream>>>(seqs, lnq, attn_s + i*DIM, attn_b + i*DIM);
    // Q projection (input = LN output), -> qkv cols 0..127
    gemm_kernel<0,0,0><<<dim3(4, N/32), 256, 0, stream>>>(
        lnq, 128, Wqkv + (size_t)i*384*128, bqkv + i*384, qkv, 384, nullptr, nullptr);
    // K,V projections (input = pre-LN seqs), -> qkv cols 128..383
    gemm_kernel<0,0,0><<<dim3(8, N/32), 256, 0, stream>>>(
        seqs, 128, Wqkv + (size_t)i*384*128 + 128*128, bqkv + i*384 + 128, qkv + 128, 384, nullptr, nullptr);
    attn_kernel<<<256*2, 256, 0, stream>>>(qkv);
    // Wo projection + residual(lnq) -> seqs
    gemm_kernel<0,1,0><<<dim3(4, N/32), 256, 0, stream>>>(
        qkv, 384, Wo + (size_t)i*128*128, bo + i*DIM, seqs, 128, lnq, nullptr);
    ln_kernel<<<N/4, 256, 0, stream>>>(seqs, lnq, ffn_s + i*DIM, ffn_b + i*DIM);
    // FFN1 relu -> qkv (packed N x 128)
    gemm_kernel<1,0,0><<<dim3(4, N/32), 256, 0, stream>>>(
        lnq, 128, W1 + (size_t)i*128*128, b1 + i*DIM, qkv, 128, nullptr, nullptr);
    // FFN2 + residual(lnq) + row mask -> seqs
    gemm_kernel<0,1,1><<<dim3(4, N/32), 256, 0, stream>>>(
        qkv, 128, W2 + (size_t)i*128*128, b2 + i*DIM, seqs, 128, lnq, lsq);
  }

  final_kernel<<<N/4, 256, 0, stream>>>(seqs, lsq, nbr, item, user,
                                        last_s, last_b, iui_s, iui_b, out);
}

// Round 2
// 652.702 us; speedup vs baseline: 1.8870x; 1.8870x over previous
//
#include <hip/hip_runtime.h>
#include <hip/hip_bf16.h>

#define L_SEQ 200
#define DIM 128
#define NROWS (256*200)

typedef __attribute__((ext_vector_type(8))) short bf16x8;
typedef __attribute__((ext_vector_type(4))) float f32x4;

__device__ __forceinline__ float wave_sum(float v){
  #pragma unroll
  for (int o = 32; o; o >>= 1) v += __shfl_xor(v, o);
  return v;
}

__device__ __forceinline__ short f2bf(float f){
  union { float f; unsigned u; } x; x.f = f;
  unsigned r = x.u + 0x7fffu + ((x.u >> 16) & 1u);
  return (short)(r >> 16);
}

// seqs = item_emb[log_seqs]*sqrt(D) + pos_emb, masked where id==0
__global__ void embed_kernel(const int* __restrict__ lsq, const float* __restrict__ item,
                             const float* __restrict__ pos, float* __restrict__ seqs){
  int r = blockIdx.x, d = threadIdx.x;
  int it = lsq[r];
  float v = item[(size_t)it*DIM + d] * 11.313708498984761f + pos[(r % L_SEQ)*DIM + d];
  seqs[(size_t)r*DIM + d] = it ? v : 0.f;
}

// per-row layernorm, one wave per row
__global__ __launch_bounds__(256) void ln_kernel(const float* __restrict__ in, float* __restrict__ out,
                                                 const float* __restrict__ s, const float* __restrict__ b){
  int wave = threadIdx.x >> 6, lane = threadIdx.x & 63;
  size_t r = (size_t)blockIdx.x*4 + wave;
  float2 v = ((const float2*)(in + r*DIM))[lane];
  float mu = wave_sum(v.x + v.y) * (1.f/DIM);
  float dx = v.x - mu, dy = v.y - mu;
  float var = wave_sum(dx*dx + dy*dy) * (1.f/DIM);
  float inv = 1.f / sqrtf(var + 1e-8f);
  float2 sc = ((const float2*)s)[lane];
  float2 bc = ((const float2*)b)[lane];
  float2 o;
  o.x = dx*inv*sc.x + bc.x;
  o.y = dy*inv*sc.y + bc.y;
  ((float2*)(out + r*DIM))[lane] = o;
}

// C[M x Ncols] = A[M x 128] @ W[Ncols x 128]^T + bias (+res) (relu) (*rowmask)
template<int RELU, int RES, int MASK>
__global__ __launch_bounds__(256) void gemm_kernel(
    const float* __restrict__ A, int lda,
    const float* __restrict__ W, const float* __restrict__ bias,
    float* __restrict__ C, int ldc,
    const float* __restrict__ res,
    const int* __restrict__ lsq){
  __shared__ float As[32][132];
  __shared__ float Bs[32][132];
  int row0 = blockIdx.y * 32, col0 = blockIdx.x * 32;
  int t = threadIdx.x;
  #pragma unroll
  for (int i = 0; i < 16; ++i) {
    int idx = t + i*256;
    int rr = idx >> 7, cc = idx & 127;
    As[rr][cc] = A[(size_t)(row0 + rr)*lda + cc];
    Bs[rr][cc] = W[(size_t)(col0 + rr)*128 + cc];
  }
  __syncthreads();
  int tx = t & 15, ty = t >> 4;
  float acc00 = 0.f, acc01 = 0.f, acc10 = 0.f, acc11 = 0.f;
  #pragma unroll
  for (int k4 = 0; k4 < 32; ++k4) {
    float4 a0 = *(const float4*)&As[ty][k4*4];
    float4 a1 = *(const float4*)&As[ty+16][k4*4];
    float4 b0 = *(const float4*)&Bs[tx][k4*4];
    float4 b1 = *(const float4*)&Bs[tx+16][k4*4];
    acc00 += a0.x*b0.x + a0.y*b0.y + a0.z*b0.z + a0.w*b0.w;
    acc01 += a0.x*b1.x + a0.y*b1.y + a0.z*b1.z + a0.w*b1.w;
    acc10 += a1.x*b0.x + a1.y*b0.y + a1.z*b0.z + a1.w*b0.w;
    acc11 += a1.x*b1.x + a1.y*b1.y + a1.z*b1.z + a1.w*b1.w;
  }
  float accs[2][2] = {{acc00, acc01}, {acc10, acc11}};
  #pragma unroll
  for (int i = 0; i < 2; ++i) {
    int rr = row0 + ty + 16*i;
    #pragma unroll
    for (int j = 0; j < 2; ++j) {
      int cc = col0 + tx + 16*j;
      float v = accs[i][j] + bias[cc];
      if (RELU) v = fmaxf(v, 0.f);
      if (RES)  v += res[(size_t)rr*DIM + cc];
      if (MASK) { if (lsq[rr] == 0) v = 0.f; }
      C[(size_t)rr*ldc + cc] = v;
    }
  }
}

// MFMA causal attention for one (batch, head). qkv rows: Q(128)|K(128)|V(128).
// Head h uses cols h*64.. of each slot; output overwrites the Q slot.
// 8 waves; wave w handles q-tiles {w, w+8}. All 13 k-tiles computed, causally masked.
__global__ __launch_bounds__(512) void attn_kernel(float* __restrict__ qkv){
  __shared__ short Ks[224*64];     // swizzled row-major [k][d], 28672 B
  __shared__ short Vt[64*224];     // swizzled transposed [d][k], 28672 B
  __shared__ short Ps[8][16*232];  // per-wave P [q][k], stride 232, 59392 B
  const int b = blockIdx.x >> 1, h = blockIdx.x & 1;
  float* base = qkv + (size_t)b*L_SEQ*384 + h*64;   // Q slot base for this head
  const float* baseK = base + 128;
  const float* baseV = base + 256;
  const int t = threadIdx.x;
  char* KsB = (char*)Ks;
  char* VtB = (char*)Vt;

  // stage K (bf16, swizzled) and V^T (bf16, swizzled); rows/cols >= 200 zero
  for (int idx = t; idx < 224*16; idx += 512) {
    int row = idx >> 4, c4 = idx & 15;
    float4 kv = {0.f,0.f,0.f,0.f}, vv = {0.f,0.f,0.f,0.f};
    if (row < L_SEQ) {
      kv = *(const float4*)(baseK + (size_t)row*384 + c4*4);
      vv = *(const float4*)(baseV + (size_t)row*384 + c4*4);
    }
    short4 ks4; ks4.x = f2bf(kv.x); ks4.y = f2bf(kv.y); ks4.z = f2bf(kv.z); ks4.w = f2bf(kv.w);
    int kbyte = (row*128 + c4*8) ^ ((row & 7) << 4);
    *(short4*)(KsB + kbyte) = ks4;
    float vval[4] = {vv.x, vv.y, vv.z, vv.w};
    #pragma unroll
    for (int i2 = 0; i2 < 4; ++i2) {
      int d = c4*4 + i2;
      int vbyte = (d*448 + row*2) ^ ((d & 7) << 4);
      *(short*)(VtB + vbyte) = f2bf(vval[i2]);
    }
  }
  __syncthreads();

  const int w = t >> 6, l = t & 63;
  const int col = l & 15, g = l >> 4, g4 = g * 4;
  char* PB = (char*)Ps[w];

  const int ntiles = (w < 5) ? 2 : 1;
  for (int j = 0; j < ntiles; ++j) {
    const int qt = w + 8*j;
    // load + scale + convert Q fragments (A operand, 2 k-chunks of 32)
    bf16x8 qf[2];
    {
      int gr = qt*16 + col;
      #pragma unroll
      for (int c = 0; c < 2; ++c) {
        float tmp[8] = {0.f,0.f,0.f,0.f,0.f,0.f,0.f,0.f};
        if (gr < L_SEQ) {
          const float* qp = base + (size_t)gr*384 + c*32 + g*8;
          float4 x0 = *(const float4*)qp;
          float4 x1 = *(const float4*)(qp + 4);
          tmp[0]=x0.x; tmp[1]=x0.y; tmp[2]=x0.z; tmp[3]=x0.w;
          tmp[4]=x1.x; tmp[5]=x1.y; tmp[6]=x1.z; tmp[7]=x1.w;
        }
        bf16x8 q;
        #pragma unroll
        for (int e = 0; e < 8; ++e) q[e] = f2bf(tmp[e] * 0.125f);
        qf[c] = q;
      }
    }
    // S = Q @ K^T over all 13 k-tiles
    f32x4 sc[13];
    #pragma unroll
    for (int kt = 0; kt < 13; ++kt) {
      f32x4 a = {0.f,0.f,0.f,0.f};
      #pragma unroll
      for (int c = 0; c < 2; ++c) {
        int row = kt*16 + col;
        int byte = (row*128 + c*64 + g*16) ^ ((row & 7) << 4);
        bf16x8 kf = *(bf16x8*)(KsB + byte);
        a = __builtin_amdgcn_mfma_f32_16x16x32_bf16(qf[c], kf, a, 0, 0, 0);
      }
      sc[kt] = a;
    }
    // causal mask + row softmax (rows = g4+r, cols across lanes&kt)
    float m[4] = {-1e30f,-1e30f,-1e30f,-1e30f};
    #pragma unroll
    for (int kt = 0; kt < 13; ++kt)
      #pragma unroll
      for (int r = 0; r < 4; ++r) {
        bool ok = (kt < qt) || ((kt == qt) && (col <= g4 + r));
        if (!ok) sc[kt][r] = -1e30f;
        m[r] = fmaxf(m[r], sc[kt][r]);
      }
    #pragma unroll
    for (int r = 0; r < 4; ++r) {
      #pragma unroll
      for (int o = 1; o <= 8; o <<= 1) m[r] = fmaxf(m[r], __shfl_xor(m[r], o));
    }
    float s[4] = {0.f,0.f,0.f,0.f};
    #pragma unroll
    for (int kt = 0; kt < 13; ++kt)
      #pragma unroll
      for (int r = 0; r < 4; ++r) {
        float e = __expf(sc[kt][r] - m[r]);
        sc[kt][r] = e;
        s[r] += e;
      }
    float inv[4];
    #pragma unroll
    for (int r = 0; r < 4; ++r) {
      #pragma unroll
      for (int o = 1; o <= 8; o <<= 1) s[r] += __shfl_xor(s[r], o);
      inv[r] = 1.f / s[r];
    }
    // store P (unnormalized exp) to per-wave LDS; zero pad cols 208..223
    #pragma unroll
    for (int kt = 0; kt < 13; ++kt)
      #pragma unroll
      for (int r = 0; r < 4; ++r)
        *(short*)(PB + ((g4 + r)*232 + kt*16 + col)*2) = f2bf(sc[kt][r]);
    #pragma unroll
    for (int r = 0; r < 4; ++r)
      *(short*)(PB + ((g4 + r)*232 + 208 + col)*2) = 0;
    asm volatile("s_waitcnt lgkmcnt(0)" ::: "memory");
    // O = P @ V  (V from transposed LDS), 4 n-tiles of 16, 7 k-chunks of 32
    f32x4 o4[4];
    #pragma unroll
    for (int nt = 0; nt < 4; ++nt) { f32x4 z = {0.f,0.f,0.f,0.f}; o4[nt] = z; }
    #pragma unroll
    for (int kc = 0; kc < 7; ++kc) {
      bf16x8 pf = *(bf16x8*)(PB + col*464 + kc*64 + g*16);
      #pragma unroll
      for (int nt = 0; nt < 4; ++nt) {
        int d = nt*16 + col;
        int byte = (d*448 + kc*64 + g*16) ^ ((d & 7) << 4);
        bf16x8 vf = *(bf16x8*)(VtB + byte);
        o4[nt] = __builtin_amdgcn_mfma_f32_16x16x32_bf16(pf, vf, o4[nt], 0, 0, 0);
      }
    }
    // write output over Q slot, normalized
    #pragma unroll
    for (int nt = 0; nt < 4; ++nt)
      #pragma unroll
      for (int r = 0; r < 4; ++r) {
        int qr = qt*16 + g4 + r;
        if (qr < L_SEQ) base[(size_t)qr*384 + nt*16 + col] = o4[nt][r] * inv[r];
      }
  }
}

// feats = LN(seqs); neighbor softmax-aggregate; out = feats + LN(agg+qn)
__global__ __launch_bounds__(256) void final_kernel(
    const float* __restrict__ seqs, const int* __restrict__ lsq, const int* __restrict__ nbr,
    const float* __restrict__ item, const float* __restrict__ user,
    const float* __restrict__ ls, const float* __restrict__ lb,
    const float* __restrict__ is_, const float* __restrict__ ib,
    float* __restrict__ out){
  int wave = threadIdx.x >> 6, lane = threadIdx.x & 63;
  size_t r = (size_t)blockIdx.x*4 + wave;
  float2 v = ((const float2*)(seqs + r*DIM))[lane];
  float mu = wave_sum(v.x + v.y) * (1.f/DIM);
  float dx = v.x - mu, dy = v.y - mu;
  float var = wave_sum(dx*dx + dy*dy) * (1.f/DIM);
  float inv = 1.f / sqrtf(var + 1e-8f);
  float2 lsc = ((const float2*)ls)[lane], lbc = ((const float2*)lb)[lane];
  float fx = dx*inv*lsc.x + lbc.x;
  float fy = dy*inv*lsc.y + lbc.y;

  int it = lsq[r];
  float2 qn = ((const float2*)(item + (size_t)it*DIM))[lane];
  float2 kn[10]; float scn[10];
  #pragma unroll
  for (int n = 0; n < 10; ++n) {
    int idx = nbr[r*10 + n];
    kn[n] = ((const float2*)(user + (size_t)idx*DIM))[lane];
    float p = wave_sum(qn.x*kn[n].x + qn.y*kn[n].y);
    scn[n] = idx ? p * 0.08838834764831845f : -1.0e9f;
  }
  float m = scn[0];
  #pragma unroll
  for (int n = 1; n < 10; ++n) m = fmaxf(m, scn[n]);
  float w[10], sum = 0.f;
  #pragma unroll
  for (int n = 0; n < 10; ++n) { w[n] = expf(scn[n] - m); sum += w[n]; }
  float invs = 1.f / sum;
  float ax = 0.f, ay = 0.f;
  #pragma unroll
  for (int n = 0; n < 10; ++n) { ax += w[n]*kn[n].x; ay += w[n]*kn[n].y; }
  ax = ax*invs + qn.x;
  ay = ay*invs + qn.y;
  float mu2 = wave_sum(ax + ay) * (1.f/DIM);
  float dx2 = ax - mu2, dy2 = ay - mu2;
  float var2 = wave_sum(dx2*dx2 + dy2*dy2) * (1.f/DIM);
  float inv2 = 1.f / sqrtf(var2 + 1e-8f);
  float2 isc = ((const float2*)is_)[lane], ibc = ((const float2*)ib)[lane];
  float2 o;
  o.x = fx + dx2*inv2*isc.x + ibc.x;
  o.y = fy + dy2*inv2*isc.y + ibc.y;
  ((float2*)(out + r*DIM))[lane] = o;
}

extern "C" void kernel_launch(void* const* d_in, const int* in_sizes, int n_in,
                              void* d_out, int out_size, void* d_ws, size_t ws_size,
                              hipStream_t stream) {
  const int*   lsq    = (const int*)d_in[0];
  const int*   nbr    = (const int*)d_in[1];
  const float* item   = (const float*)d_in[2];
  const float* user   = (const float*)d_in[3];
  const float* pos    = (const float*)d_in[4];
  const float* attn_s = (const float*)d_in[5];
  const float* attn_b = (const float*)d_in[6];
  const float* Wqkv   = (const float*)d_in[7];
  const float* bqkv   = (const float*)d_in[8];
  const float* Wo     = (const float*)d_in[9];
  const float* bo     = (const float*)d_in[10];
  const float* ffn_s  = (const float*)d_in[11];
  const float* ffn_b  = (const float*)d_in[12];
  const float* W1     = (const float*)d_in[13];
  const float* b1     = (const float*)d_in[14];
  const float* W2     = (const float*)d_in[15];
  const float* b2     = (const float*)d_in[16];
  const float* last_s = (const float*)d_in[17];
  const float* last_b = (const float*)d_in[18];
  const float* iui_s  = (const float*)d_in[19];
  const float* iui_b  = (const float*)d_in[20];
  float* out = (float*)d_out;

  const int N = NROWS;  // 51200 rows
  float* seqs = (float*)d_ws;                   // N x 128
  float* lnq  = seqs + (size_t)N*DIM;           // N x 128
  float* qkv  = lnq  + (size_t)N*DIM;           // N x 384

  embed_kernel<<<N, DIM, 0, stream>>>(lsq, item, pos, seqs);

  for (int i = 0; i < 2; ++i) {
    ln_kernel<<<N/4, 256, 0, stream>>>(seqs, lnq, attn_s + i*DIM, attn_b + i*DIM);
    // Q projection (input = LN output) -> qkv cols 0..127
    gemm_kernel<0,0,0><<<dim3(4, N/32), 256, 0, stream>>>(
        lnq, 128, Wqkv + (size_t)i*384*128, bqkv + i*384, qkv, 384, nullptr, nullptr);
    // K,V projections (input = pre-LN seqs) -> qkv cols 128..383
    gemm_kernel<0,0,0><<<dim3(8, N/32), 256, 0, stream>>>(
        seqs, 128, Wqkv + (size_t)i*384*128 + 128*128, bqkv + i*384 + 128, qkv + 128, 384, nullptr, nullptr);
    attn_kernel<<<256*2, 512, 0, stream>>>(qkv);
    // Wo projection + residual(lnq) -> seqs
    gemm_kernel<0,1,0><<<dim3(4, N/32), 256, 0, stream>>>(
        qkv, 384, Wo + (size_t)i*128*128, bo + i*DIM, seqs, 128, lnq, nullptr);
    ln_kernel<<<N/4, 256, 0, stream>>>(seqs, lnq, ffn_s + i*DIM, ffn_b + i*DIM);
    // FFN1 relu -> qkv (packed N x 128)
    gemm_kernel<1,0,0><<<dim3(4, N/32), 256, 0, stream>>>(
        lnq, 128, W1 + (size_t)i*128*128, b1 + i*DIM, qkv, 128, nullptr, nullptr);
    // FFN2 + residual(lnq) + row mask -> seqs
    gemm_kernel<0,1,1><<<dim3(4, N/32), 256, 0, stream>>>(
        qkv, 128, W2 + (size_t)i*128*128, b2 + i*DIM, seqs, 128, lnq, lsq);
  }

  final_kernel<<<N/4, 256, 0, stream>>>(seqs, lsq, nbr, item, user,
                                        last_s, last_b, iui_s, iui_b, out);
}

// Round 4
// 322.709 us; speedup vs baseline: 3.8166x; 2.0226x over previous
//
#include <hip/hip_runtime.h>
#include <hip/hip_bf16.h>

#define L_SEQ 200
#define DIM 128
#define NROWS (256*200)

typedef __attribute__((ext_vector_type(8))) short bf16x8;
typedef __attribute__((ext_vector_type(4))) float f32x4;

__device__ __forceinline__ float wave_sum(float v){
  #pragma unroll
  for (int o = 32; o; o >>= 1) v += __shfl_xor(v, o);
  return v;
}

__device__ __forceinline__ short f2bf(float f){
  union { float f; unsigned u; } x; x.f = f;
  unsigned r = x.u + 0x7fffu + ((x.u >> 16) & 1u);
  return (short)(r >> 16);
}

// fp32 -> bf16 weight conversion
__global__ void cvt_kernel(const float* __restrict__ src, short* __restrict__ dst, int n){
  int i = blockIdx.x*256 + threadIdx.x;
  if (i < n) dst[i] = f2bf(src[i]);
}

// seqs = item_emb[log_seqs]*sqrt(D) + pos_emb, masked where id==0
__global__ void embed_kernel(const int* __restrict__ lsq, const float* __restrict__ item,
                             const float* __restrict__ pos, float* __restrict__ seqs){
  int r = blockIdx.x, d = threadIdx.x;
  int it = lsq[r];
  float v = item[(size_t)it*DIM + d] * 11.313708498984761f + pos[(r % L_SEQ)*DIM + d];
  seqs[(size_t)r*DIM + d] = it ? v : 0.f;
}

// per-row layernorm, one wave per row
__global__ __launch_bounds__(256) void ln_kernel(const float* __restrict__ in, float* __restrict__ out,
                                                 const float* __restrict__ s, const float* __restrict__ b){
  int wave = threadIdx.x >> 6, lane = threadIdx.x & 63;
  size_t r = (size_t)blockIdx.x*4 + wave;
  float2 v = ((const float2*)(in + r*DIM))[lane];
  float mu = wave_sum(v.x + v.y) * (1.f/DIM);
  float dx = v.x - mu, dy = v.y - mu;
  float var = wave_sum(dx*dx + dy*dy) * (1.f/DIM);
  float inv = 1.f / sqrtf(var + 1e-8f);
  float2 sc = ((const float2*)s)[lane];
  float2 bc = ((const float2*)b)[lane];
  float2 o;
  o.x = dx*inv*sc.x + bc.x;
  o.y = dy*inv*sc.y + bc.y;
  ((float2*)(out + r*DIM))[lane] = o;
}

// MFMA GEMM: C[M x N] = A[M x 128](fp32) @ Wb[N x 128](bf16)^T + bias (+res)(relu)(*rowmask)
// BM=BN=128, K=128 single tile. 8 waves (2m x 4n), each 64x32 out.
template<int RELU, int RES, int MASK>
__global__ __launch_bounds__(512) void mgemm_kernel(
    const float* __restrict__ A, int lda,
    const short* __restrict__ Wb, const float* __restrict__ bias,
    float* __restrict__ C, int ldc,
    const float* __restrict__ res,
    const int* __restrict__ lsq){
  __shared__ short As[128*128];   // swizzled, row stride 256B
  __shared__ short Bs[128*128];
  char* AsB = (char*)As;
  char* BsB = (char*)Bs;
  const int row0 = blockIdx.y * 128, col0 = blockIdx.x * 128;
  const int t = threadIdx.x;

  // stage A: fp32 -> bf16, 512 threads x 8 float4 (16384 elems)
  #pragma unroll
  for (int i = 0; i < 8; ++i) {
    int flat = t*4 + i*2048;           // element index in 128x128
    int rr = flat >> 7, cc = flat & 127;
    float4 a4 = *(const float4*)(A + (size_t)(row0 + rr)*lda + cc);
    short4 s4; s4.x = f2bf(a4.x); s4.y = f2bf(a4.y); s4.z = f2bf(a4.z); s4.w = f2bf(a4.w);
    int byte = (rr*256 + cc*2) ^ ((rr & 7) << 4);
    *(short4*)(AsB + byte) = s4;
  }
  // stage B: bf16 weights, 512 threads x 4 x short8 (16384 elems)
  #pragma unroll
  for (int i = 0; i < 4; ++i) {
    int flat = t*8 + i*4096;
    int rr = flat >> 7, cc = flat & 127;
    bf16x8 s8 = *(const bf16x8*)(Wb + (size_t)(col0 + rr)*128 + cc);
    int byte = (rr*256 + cc*2) ^ ((rr & 7) << 4);
    *(bf16x8*)(BsB + byte) = s8;
  }
  __syncthreads();

  const int w = t >> 6, l = t & 63;
  const int wm = w >> 2, wn = w & 3;           // 2 x 4 wave grid
  const int col = l & 15, g = l >> 4;
  const int mbase = wm*64, nbase = wn*32;

  f32x4 acc[4][2];
  #pragma unroll
  for (int mf = 0; mf < 4; ++mf)
    #pragma unroll
    for (int nf = 0; nf < 2; ++nf) { f32x4 z = {0.f,0.f,0.f,0.f}; acc[mf][nf] = z; }

  #pragma unroll
  for (int kc = 0; kc < 4; ++kc) {
    bf16x8 af[4], bfr[2];
    #pragma unroll
    for (int mf = 0; mf < 4; ++mf) {
      int rr = mbase + mf*16 + col;
      int byte = (rr*256 + kc*64 + g*16) ^ ((rr & 7) << 4);
      af[mf] = *(bf16x8*)(AsB + byte);
    }
    #pragma unroll
    for (int nf = 0; nf < 2; ++nf) {
      int rr = nbase + nf*16 + col;
      int byte = (rr*256 + kc*64 + g*16) ^ ((rr & 7) << 4);
      bfr[nf] = *(bf16x8*)(BsB + byte);
    }
    #pragma unroll
    for (int mf = 0; mf < 4; ++mf)
      #pragma unroll
      for (int nf = 0; nf < 2; ++nf)
        acc[mf][nf] = __builtin_amdgcn_mfma_f32_16x16x32_bf16(af[mf], bfr[nf], acc[mf][nf], 0, 0, 0);
  }

  // epilogue
  #pragma unroll
  for (int mf = 0; mf < 4; ++mf) {
    #pragma unroll
    for (int r = 0; r < 4; ++r) {
      int rr = row0 + mbase + mf*16 + g*4 + r;
      #pragma unroll
      for (int nf = 0; nf < 2; ++nf) {
        int cc = col0 + nbase + nf*16 + col;
        float v = acc[mf][nf][r] + bias[cc];
        if (RELU) v = fmaxf(v, 0.f);
        if (RES)  v += res[(size_t)rr*DIM + cc];
        if (MASK) { if (lsq[rr] == 0) v = 0.f; }
        C[(size_t)rr*ldc + cc] = v;
      }
    }
  }
}

// MFMA causal attention for one (batch, head). qkv rows: Q(128)|K(128)|V(128).
__global__ __launch_bounds__(512) void attn_kernel(float* __restrict__ qkv){
  __shared__ short Ks[224*64];
  __shared__ short Vt[64*224];
  __shared__ short Ps[8][16*232];
  const int b = blockIdx.x >> 1, h = blockIdx.x & 1;
  float* base = qkv + (size_t)b*L_SEQ*384 + h*64;
  const float* baseK = base + 128;
  const float* baseV = base + 256;
  const int t = threadIdx.x;
  char* KsB = (char*)Ks;
  char* VtB = (char*)Vt;

  for (int idx = t; idx < 224*16; idx += 512) {
    int row = idx >> 4, c4 = idx & 15;
    float4 kv = {0.f,0.f,0.f,0.f}, vv = {0.f,0.f,0.f,0.f};
    if (row < L_SEQ) {
      kv = *(const float4*)(baseK + (size_t)row*384 + c4*4);
      vv = *(const float4*)(baseV + (size_t)row*384 + c4*4);
    }
    short4 ks4; ks4.x = f2bf(kv.x); ks4.y = f2bf(kv.y); ks4.z = f2bf(kv.z); ks4.w = f2bf(kv.w);
    int kbyte = (row*128 + c4*8) ^ ((row & 7) << 4);
    *(short4*)(KsB + kbyte) = ks4;
    float vval[4] = {vv.x, vv.y, vv.z, vv.w};
    #pragma unroll
    for (int i2 = 0; i2 < 4; ++i2) {
      int d = c4*4 + i2;
      int vbyte = (d*448 + row*2) ^ ((d & 7) << 4);
      *(short*)(VtB + vbyte) = f2bf(vval[i2]);
    }
  }
  __syncthreads();

  const int w = t >> 6, l = t & 63;
  const int col = l & 15, g = l >> 4, g4 = g * 4;
  char* PB = (char*)Ps[w];

  const int ntiles = (w < 5) ? 2 : 1;
  for (int j = 0; j < ntiles; ++j) {
    const int qt = w + 8*j;
    bf16x8 qf[2];
    {
      int gr = qt*16 + col;
      #pragma unroll
      for (int c = 0; c < 2; ++c) {
        float tmp[8] = {0.f,0.f,0.f,0.f,0.f,0.f,0.f,0.f};
        if (gr < L_SEQ) {
          const float* qp = base + (size_t)gr*384 + c*32 + g*8;
          float4 x0 = *(const float4*)qp;
          float4 x1 = *(const float4*)(qp + 4);
          tmp[0]=x0.x; tmp[1]=x0.y; tmp[2]=x0.z; tmp[3]=x0.w;
          tmp[4]=x1.x; tmp[5]=x1.y; tmp[6]=x1.z; tmp[7]=x1.w;
        }
        bf16x8 q;
        #pragma unroll
        for (int e = 0; e < 8; ++e) q[e] = f2bf(tmp[e] * 0.125f);
        qf[c] = q;
      }
    }
    f32x4 sc[13];
    #pragma unroll
    for (int kt = 0; kt < 13; ++kt) {
      f32x4 a = {0.f,0.f,0.f,0.f};
      #pragma unroll
      for (int c = 0; c < 2; ++c) {
        int row = kt*16 + col;
        int byte = (row*128 + c*64 + g*16) ^ ((row & 7) << 4);
        bf16x8 kf = *(bf16x8*)(KsB + byte);
        a = __builtin_amdgcn_mfma_f32_16x16x32_bf16(qf[c], kf, a, 0, 0, 0);
      }
      sc[kt] = a;
    }
    float m[4] = {-1e30f,-1e30f,-1e30f,-1e30f};
    #pragma unroll
    for (int kt = 0; kt < 13; ++kt)
      #pragma unroll
      for (int r = 0; r < 4; ++r) {
        bool ok = (kt < qt) || ((kt == qt) && (col <= g4 + r));
        if (!ok) sc[kt][r] = -1e30f;
        m[r] = fmaxf(m[r], sc[kt][r]);
      }
    #pragma unroll
    for (int r = 0; r < 4; ++r) {
      #pragma unroll
      for (int o = 1; o <= 8; o <<= 1) m[r] = fmaxf(m[r], __shfl_xor(m[r], o));
    }
    float s[4] = {0.f,0.f,0.f,0.f};
    #pragma unroll
    for (int kt = 0; kt < 13; ++kt)
      #pragma unroll
      for (int r = 0; r < 4; ++r) {
        float e = __expf(sc[kt][r] - m[r]);
        sc[kt][r] = e;
        s[r] += e;
      }
    float inv[4];
    #pragma unroll
    for (int r = 0; r < 4; ++r) {
      #pragma unroll
      for (int o = 1; o <= 8; o <<= 1) s[r] += __shfl_xor(s[r], o);
      inv[r] = 1.f / s[r];
    }
    #pragma unroll
    for (int kt = 0; kt < 13; ++kt)
      #pragma unroll
      for (int r = 0; r < 4; ++r)
        *(short*)(PB + ((g4 + r)*232 + kt*16 + col)*2) = f2bf(sc[kt][r]);
    #pragma unroll
    for (int r = 0; r < 4; ++r)
      *(short*)(PB + ((g4 + r)*232 + 208 + col)*2) = 0;
    asm volatile("s_waitcnt lgkmcnt(0)" ::: "memory");
    f32x4 o4[4];
    #pragma unroll
    for (int nt = 0; nt < 4; ++nt) { f32x4 z = {0.f,0.f,0.f,0.f}; o4[nt] = z; }
    #pragma unroll
    for (int kc = 0; kc < 7; ++kc) {
      bf16x8 pf = *(bf16x8*)(PB + col*464 + kc*64 + g*16);
      #pragma unroll
      for (int nt = 0; nt < 4; ++nt) {
        int d = nt*16 + col;
        int byte = (d*448 + kc*64 + g*16) ^ ((d & 7) << 4);
        bf16x8 vf = *(bf16x8*)(VtB + byte);
        o4[nt] = __builtin_amdgcn_mfma_f32_16x16x32_bf16(pf, vf, o4[nt], 0, 0, 0);
      }
    }
    #pragma unroll
    for (int nt = 0; nt < 4; ++nt)
      #pragma unroll
      for (int r = 0; r < 4; ++r) {
        int qr = qt*16 + g4 + r;
        if (qr < L_SEQ) base[(size_t)qr*384 + nt*16 + col] = o4[nt][r] * inv[r];
      }
  }
}

// feats = LN(seqs); neighbor softmax-aggregate; out = feats + LN(agg+qn)
__global__ __launch_bounds__(256) void final_kernel(
    const float* __restrict__ seqs, const int* __restrict__ lsq, const int* __restrict__ nbr,
    const float* __restrict__ item, const float* __restrict__ user,
    const float* __restrict__ ls, const float* __restrict__ lb,
    const float* __restrict__ is_, const float* __restrict__ ib,
    float* __restrict__ out){
  int wave = threadIdx.x >> 6, lane = threadIdx.x & 63;
  size_t r = (size_t)blockIdx.x*4 + wave;
  float2 v = ((const float2*)(seqs + r*DIM))[lane];
  float mu = wave_sum(v.x + v.y) * (1.f/DIM);
  float dx = v.x - mu, dy = v.y - mu;
  float var = wave_sum(dx*dx + dy*dy) * (1.f/DIM);
  float inv = 1.f / sqrtf(var + 1e-8f);
  float2 lsc = ((const float2*)ls)[lane], lbc = ((const float2*)lb)[lane];
  float fx = dx*inv*lsc.x + lbc.x;
  float fy = dy*inv*lsc.y + lbc.y;

  int it = lsq[r];
  float2 qn = ((const float2*)(item + (size_t)it*DIM))[lane];
  float2 kn[10]; float scn[10];
  #pragma unroll
  for (int n = 0; n < 10; ++n) {
    int idx = nbr[r*10 + n];
    kn[n] = ((const float2*)(user + (size_t)idx*DIM))[lane];
    float p = wave_sum(qn.x*kn[n].x + qn.y*kn[n].y);
    scn[n] = idx ? p * 0.08838834764831845f : -1.0e9f;
  }
  float m = scn[0];
  #pragma unroll
  for (int n = 1; n < 10; ++n) m = fmaxf(m, scn[n]);
  float w[10], sum = 0.f;
  #pragma unroll
  for (int n = 0; n < 10; ++n) { w[n] = expf(scn[n] - m); sum += w[n]; }
  float invs = 1.f / sum;
  float ax = 0.f, ay = 0.f;
  #pragma unroll
  for (int n = 0; n < 10; ++n) { ax += w[n]*kn[n].x; ay += w[n]*kn[n].y; }
  ax = ax*invs + qn.x;
  ay = ay*invs + qn.y;
  float mu2 = wave_sum(ax + ay) * (1.f/DIM);
  float dx2 = ax - mu2, dy2 = ay - mu2;
  float var2 = wave_sum(dx2*dx2 + dy2*dy2) * (1.f/DIM);
  float inv2 = 1.f / sqrtf(var2 + 1e-8f);
  float2 isc = ((const float2*)is_)[lane], ibc = ((const float2*)ib)[lane];
  float2 o;
  o.x = fx + dx2*inv2*isc.x + ibc.x;
  o.y = fy + dy2*inv2*isc.y + ibc.y;
  ((float2*)(out + r*DIM))[lane] = o;
}

extern "C" void kernel_launch(void* const* d_in, const int* in_sizes, int n_in,
                              void* d_out, int out_size, void* d_ws, size_t ws_size,
                              hipStream_t stream) {
  const int*   lsq    = (const int*)d_in[0];
  const int*   nbr    = (const int*)d_in[1];
  const float* item   = (const float*)d_in[2];
  const float* user   = (const float*)d_in[3];
  const float* pos    = (const float*)d_in[4];
  const float* attn_s = (const float*)d_in[5];
  const float* attn_b = (const float*)d_in[6];
  const float* Wqkv   = (const float*)d_in[7];
  const float* bqkv   = (const float*)d_in[8];
  const float* Wo     = (const float*)d_in[9];
  const float* bo     = (const float*)d_in[10];
  const float* ffn_s  = (const float*)d_in[11];
  const float* ffn_b  = (const float*)d_in[12];
  const float* W1     = (const float*)d_in[13];
  const float* b1     = (const float*)d_in[14];
  const float* W2     = (const float*)d_in[15];
  const float* b2     = (const float*)d_in[16];
  const float* last_s = (const float*)d_in[17];
  const float* last_b = (const float*)d_in[18];
  const float* iui_s  = (const float*)d_in[19];
  const float* iui_b  = (const float*)d_in[20];
  float* out = (float*)d_out;

  const int N = NROWS;  // 51200 rows
  float* seqs = (float*)d_ws;                   // N x 128 f32
  float* lnq  = seqs + (size_t)N*DIM;           // N x 128 f32
  float* qkv  = lnq  + (size_t)N*DIM;           // N x 384 f32
  // bf16 weights live at the head of d_out (~0.4 MB of 26 MB); they are
  // fully consumed before final_kernel overwrites all of d_out.
  short* wqkv_b = (short*)d_out;                  // 2 x 384 x 128 bf16
  short* wo_b   = wqkv_b + 2*384*128;             // 2 x 128 x 128
  short* w1_b   = wo_b   + 2*128*128;
  short* w2_b   = w1_b   + 2*128*128;

  cvt_kernel<<<(2*384*128+255)/256, 256, 0, stream>>>(Wqkv, wqkv_b, 2*384*128);
  cvt_kernel<<<(2*128*128+255)/256, 256, 0, stream>>>(Wo,   wo_b,   2*128*128);
  cvt_kernel<<<(2*128*128+255)/256, 256, 0, stream>>>(W1,   w1_b,   2*128*128);
  cvt_kernel<<<(2*128*128+255)/256, 256, 0, stream>>>(W2,   w2_b,   2*128*128);

  embed_kernel<<<N, DIM, 0, stream>>>(lsq, item, pos, seqs);

  for (int i = 0; i < 2; ++i) {
    ln_kernel<<<N/4, 256, 0, stream>>>(seqs, lnq, attn_s + i*DIM, attn_b + i*DIM);
    // Q projection (input = LN output) -> qkv cols 0..127
    mgemm_kernel<0,0,0><<<dim3(1, N/128), 512, 0, stream>>>(
        lnq, 128, wqkv_b + (size_t)i*384*128, bqkv + i*384, qkv, 384, nullptr, nullptr);
    // K,V projections (input = pre-LN seqs) -> qkv cols 128..383
    mgemm_kernel<0,0,0><<<dim3(2, N/128), 512, 0, stream>>>(
        seqs, 128, wqkv_b + (size_t)i*384*128 + 128*128, bqkv + i*384 + 128, qkv + 128, 384, nullptr, nullptr);
    attn_kernel<<<256*2, 512, 0, stream>>>(qkv);
    // Wo projection + residual(lnq) -> seqs
    mgemm_kernel<0,1,0><<<dim3(1, N/128), 512, 0, stream>>>(
        qkv, 384, wo_b + (size_t)i*128*128, bo + i*DIM, seqs, 128, lnq, nullptr);
    ln_kernel<<<N/4, 256, 0, stream>>>(seqs, lnq, ffn_s + i*DIM, ffn_b + i*DIM);
    // FFN1 relu -> qkv (packed N x 128)
    mgemm_kernel<1,0,0><<<dim3(1, N/128), 512, 0, stream>>>(
        lnq, 128, w1_b + (size_t)i*128*128, b1 + i*DIM, qkv, 128, nullptr, nullptr);
    // FFN2 + residual(lnq) + row mask -> seqs
    mgemm_kernel<0,1,1><<<dim3(1, N/128), 512, 0, stream>>>(
        qkv, 128, w2_b + (size_t)i*128*128, b2 + i*DIM, seqs, 128, lnq, lsq);
  }

  final_kernel<<<N/4, 256, 0, stream>>>(seqs, lsq, nbr, item, user,
                                        last_s, last_b, iui_s, iui_b, out);
}

// Round 5
// 255.451 us; speedup vs baseline: 4.8215x; 1.2633x over previous
//
#include <hip/hip_runtime.h>
#include <hip/hip_bf16.h>

#define L_SEQ 200
#define DIM 128
#define NROWS (256*200)

typedef __attribute__((ext_vector_type(8))) short bf16x8;
typedef __attribute__((ext_vector_type(4))) float f32x4;

__device__ __forceinline__ float wave_sum(float v){
  #pragma unroll
  for (int o = 32; o; o >>= 1) v += __shfl_xor(v, o);
  return v;
}
__device__ __forceinline__ short f2bf(float f){
  union { float f; unsigned u; } x; x.f = f;
  unsigned r = x.u + 0x7fffu + ((x.u >> 16) & 1u);
  return (short)(r >> 16);
}
__device__ __forceinline__ float bf2f(unsigned short u){
  union { unsigned u; float f; } x; x.u = ((unsigned)u) << 16;
  return x.f;
}

// fp32 -> bf16, 4 at a time
__global__ void cvt4_kernel(const float* __restrict__ src, short* __restrict__ dst, int n4){
  int i = blockIdx.x*256 + threadIdx.x;
  if (i < n4) {
    float4 v = ((const float4*)src)[i];
    short4 s; s.x = f2bf(v.x); s.y = f2bf(v.y); s.z = f2bf(v.z); s.w = f2bf(v.w);
    ((short4*)dst)[i] = s;
  }
}

// seqs = item_b[log_seqs]*sqrt(D)+pos (masked); also lnq = LN(seqs, attn_ln0). bf16 out.
__global__ __launch_bounds__(256) void embed_ln_kernel(
    const int* __restrict__ lsq, const short* __restrict__ item_b,
    const float* __restrict__ pos, const float* __restrict__ s, const float* __restrict__ b,
    short* __restrict__ seqs_b, short* __restrict__ lnq_b){
  int wave = threadIdx.x >> 6, lane = threadIdx.x & 63;
  size_t r = (size_t)blockIdx.x*4 + wave;
  int it = lsq[r];
  ushort2 iv = ((const ushort2*)(item_b + (size_t)it*DIM))[lane];
  float2 p = ((const float2*)(pos + (r % L_SEQ)*DIM))[lane];
  float vx = 0.f, vy = 0.f;
  if (it) {
    vx = bf2f(iv.x) * 11.313708498984761f + p.x;
    vy = bf2f(iv.y) * 11.313708498984761f + p.y;
  }
  short2 sv; sv.x = f2bf(vx); sv.y = f2bf(vy);
  ((short2*)(seqs_b + r*DIM))[lane] = sv;
  float mu = wave_sum(vx + vy) * (1.f/DIM);
  float dx = vx - mu, dy = vy - mu;
  float var = wave_sum(dx*dx + dy*dy) * (1.f/DIM);
  float inv = 1.f / sqrtf(var + 1e-8f);
  float2 sc = ((const float2*)s)[lane];
  float2 bc = ((const float2*)b)[lane];
  short2 ov; ov.x = f2bf(dx*inv*sc.x + bc.x); ov.y = f2bf(dy*inv*sc.y + bc.y);
  ((short2*)(lnq_b + r*DIM))[lane] = ov;
}

// MFMA GEMM, all-bf16 I/O. C[M x N] = A @ Wb^T + bias, optional relu/res/mask,
// optional fused LayerNorm epilogue (block owns complete 128-col rows).
// QKV mode: grid.x=3, x==0 uses A0 (lnq) + 0.125 scale, x>0 uses A1 (seqs).
template<int RELU, int RES, int MASK, int LN, int WRITE_C, int QKV>
__global__ __launch_bounds__(512) void mgemm_kernel(
    const short* __restrict__ A0, const short* __restrict__ A1, int lda,
    const short* __restrict__ Wb, const float* __restrict__ bias,
    short* __restrict__ C, int ldc,
    const short* __restrict__ res, const int* __restrict__ lsq,
    const float* __restrict__ lnS, const float* __restrict__ lnB,
    short* __restrict__ lnOut){
  __shared__ short As[16384];
  __shared__ short Bs[16384];
  __shared__ float redP[2][4][128];
  __shared__ float muA[128], invA[128];
  char* AsB = (char*)As;
  char* BsB = (char*)Bs;
  const int row0 = blockIdx.y * 128, col0 = blockIdx.x * 128;
  const int t = threadIdx.x;
  const short* Ap = (QKV && blockIdx.x != 0) ? A1 : A0;

  // stage A, B: bf16 short8 loads -> swizzled LDS
  #pragma unroll
  for (int i = 0; i < 4; ++i) {
    int flat = t*8 + i*4096;
    int rr = flat >> 7, cc = flat & 127;
    bf16x8 a8 = *(const bf16x8*)(Ap + (size_t)(row0 + rr)*lda + cc);
    int byte = (rr*256 + cc*2) ^ ((rr & 7) << 4);
    *(bf16x8*)(AsB + byte) = a8;
    bf16x8 b8 = *(const bf16x8*)(Wb + (size_t)(col0 + rr)*128 + cc);
    *(bf16x8*)(BsB + byte) = b8;
  }
  __syncthreads();

  const int w = t >> 6, l = t & 63;
  const int wm = w >> 2, wn = w & 3;
  const int col = l & 15, g = l >> 4;
  const int mbase = wm*64, nbase = wn*32;

  f32x4 acc[4][2];
  #pragma unroll
  for (int mf = 0; mf < 4; ++mf)
    #pragma unroll
    for (int nf = 0; nf < 2; ++nf) { f32x4 z = {0.f,0.f,0.f,0.f}; acc[mf][nf] = z; }

  #pragma unroll
  for (int kc = 0; kc < 4; ++kc) {
    bf16x8 af[4], bfr[2];
    #pragma unroll
    for (int mf = 0; mf < 4; ++mf) {
      int rr = mbase + mf*16 + col;
      int byte = (rr*256 + kc*64 + g*16) ^ ((rr & 7) << 4);
      af[mf] = *(bf16x8*)(AsB + byte);
    }
    #pragma unroll
    for (int nf = 0; nf < 2; ++nf) {
      int rr = nbase + nf*16 + col;
      int byte = (rr*256 + kc*64 + g*16) ^ ((rr & 7) << 4);
      bfr[nf] = *(bf16x8*)(BsB + byte);
    }
    #pragma unroll
    for (int mf = 0; mf < 4; ++mf)
      #pragma unroll
      for (int nf = 0; nf < 2; ++nf)
        acc[mf][nf] = __builtin_amdgcn_mfma_f32_16x16x32_bf16(af[mf], bfr[nf], acc[mf][nf], 0, 0, 0);
  }

  // epilogue: v = acc + bias (+relu)(+res)(mask)(Qscale); store back into acc
  float biasv[2];
  #pragma unroll
  for (int nf = 0; nf < 2; ++nf) biasv[nf] = bias[col0 + nbase + nf*16 + col];
  #pragma unroll
  for (int mf = 0; mf < 4; ++mf) {
    #pragma unroll
    for (int r = 0; r < 4; ++r) {
      int rL = mbase + mf*16 + g*4 + r;
      int rr = row0 + rL;
      bool zr = MASK ? (lsq[rr] == 0) : false;
      #pragma unroll
      for (int nf = 0; nf < 2; ++nf) {
        int cc = col0 + nbase + nf*16 + col;
        float v = acc[mf][nf][r] + biasv[nf];
        if (RELU) v = fmaxf(v, 0.f);
        if (RES)  v += bf2f(((const unsigned short*)res)[(size_t)rr*DIM + (cc - col0)]);
        if (MASK && zr) v = 0.f;
        if (QKV && blockIdx.x == 0) v *= 0.125f;
        acc[mf][nf][r] = v;
        if (!LN) C[(size_t)rr*ldc + cc] = f2bf(v);
      }
    }
  }

  if (LN) {
    // per-row sum/sumsq: local pair-sum then butterfly over the 16 col-lanes
    #pragma unroll
    for (int mf = 0; mf < 4; ++mf) {
      #pragma unroll
      for (int r = 0; r < 4; ++r) {
        float s1 = acc[mf][0][r] + acc[mf][1][r];
        float s2 = acc[mf][0][r]*acc[mf][0][r] + acc[mf][1][r]*acc[mf][1][r];
        #pragma unroll
        for (int o = 1; o <= 8; o <<= 1) { s1 += __shfl_xor(s1, o); s2 += __shfl_xor(s2, o); }
        if (col == 0) {
          int rL = mbase + mf*16 + g*4 + r;
          redP[0][wn][rL] = s1;
          redP[1][wn][rL] = s2;
        }
      }
    }
    __syncthreads();
    if (t < 128) {
      float s1 = redP[0][0][t] + redP[0][1][t] + redP[0][2][t] + redP[0][3][t];
      float s2 = redP[1][0][t] + redP[1][1][t] + redP[1][2][t] + redP[1][3][t];
      float mu = s1 * (1.f/DIM);
      float var = s2 * (1.f/DIM) - mu*mu;
      muA[t] = mu;
      invA[t] = 1.f / sqrtf(var + 1e-8f);
    }
    __syncthreads();
    #pragma unroll
    for (int mf = 0; mf < 4; ++mf) {
      #pragma unroll
      for (int r = 0; r < 4; ++r) {
        int rL = mbase + mf*16 + g*4 + r;
        float mu = muA[rL], inv = invA[rL];
        #pragma unroll
        for (int nf = 0; nf < 2; ++nf) {
          int cL = nbase + nf*16 + col;
          float v = acc[mf][nf][r];
          float lnv = (v - mu)*inv*lnS[cL] + lnB[cL];
          lnOut[(size_t)(row0 + rL)*DIM + cL] = f2bf(lnv);
          if (WRITE_C) C[(size_t)(row0 + rL)*ldc + cL] = f2bf(v);
        }
      }
    }
  }
}

// MFMA causal attention, bf16 qkv. One block per (batch, head); out overwrites Q slot.
__global__ __launch_bounds__(512) void attn_kernel(short* __restrict__ qkv){
  __shared__ short Ks[224*64];
  __shared__ short Vt[64*224];
  __shared__ short Ps[8][16*232];
  const int b = blockIdx.x >> 1, h = blockIdx.x & 1;
  short* base = qkv + (size_t)b*L_SEQ*384 + h*64;
  const short* baseK = base + 128;
  const short* baseV = base + 256;
  const int t = threadIdx.x;
  char* KsB = (char*)Ks;
  char* VtB = (char*)Vt;

  for (int idx = t; idx < 224*8; idx += 512) {
    int row = idx >> 3, c8 = idx & 7;
    bf16x8 kv = {0,0,0,0,0,0,0,0}, vv = {0,0,0,0,0,0,0,0};
    if (row < L_SEQ) {
      kv = *(const bf16x8*)(baseK + (size_t)row*384 + c8*8);
      vv = *(const bf16x8*)(baseV + (size_t)row*384 + c8*8);
    }
    int kbyte = (row*128 + c8*16) ^ ((row & 7) << 4);
    *(bf16x8*)(KsB + kbyte) = kv;
    #pragma unroll
    for (int e = 0; e < 8; ++e) {
      int d = c8*8 + e;
      int vbyte = (d*448 + row*2) ^ ((d & 7) << 4);
      *(short*)(VtB + vbyte) = vv[e];
    }
  }
  __syncthreads();

  const int w = t >> 6, l = t & 63;
  const int col = l & 15, g = l >> 4, g4 = g * 4;
  char* PB = (char*)Ps[w];

  const int ntiles = (w < 5) ? 2 : 1;
  for (int j = 0; j < ntiles; ++j) {
    const int qt = w + 8*j;
    bf16x8 qf[2];
    {
      int gr = qt*16 + col;
      #pragma unroll
      for (int c = 0; c < 2; ++c) {
        bf16x8 q = {0,0,0,0,0,0,0,0};
        if (gr < L_SEQ) q = *(const bf16x8*)(base + (size_t)gr*384 + c*32 + g*8);
        qf[c] = q;
      }
    }
    f32x4 sc[13];
    #pragma unroll
    for (int kt = 0; kt < 13; ++kt) {
      f32x4 a = {0.f,0.f,0.f,0.f};
      #pragma unroll
      for (int c = 0; c < 2; ++c) {
        int row = kt*16 + col;
        int byte = (row*128 + c*64 + g*16) ^ ((row & 7) << 4);
        bf16x8 kf = *(bf16x8*)(KsB + byte);
        a = __builtin_amdgcn_mfma_f32_16x16x32_bf16(qf[c], kf, a, 0, 0, 0);
      }
      sc[kt] = a;
    }
    float m[4] = {-1e30f,-1e30f,-1e30f,-1e30f};
    #pragma unroll
    for (int kt = 0; kt < 13; ++kt)
      #pragma unroll
      for (int r = 0; r < 4; ++r) {
        bool ok = (kt < qt) || ((kt == qt) && (col <= g4 + r));
        if (!ok) sc[kt][r] = -1e30f;
        m[r] = fmaxf(m[r], sc[kt][r]);
      }
    #pragma unroll
    for (int r = 0; r < 4; ++r) {
      #pragma unroll
      for (int o = 1; o <= 8; o <<= 1) m[r] = fmaxf(m[r], __shfl_xor(m[r], o));
    }
    float s[4] = {0.f,0.f,0.f,0.f};
    #pragma unroll
    for (int kt = 0; kt < 13; ++kt)
      #pragma unroll
      for (int r = 0; r < 4; ++r) {
        float e = __expf(sc[kt][r] - m[r]);
        sc[kt][r] = e;
        s[r] += e;
      }
    float inv[4];
    #pragma unroll
    for (int r = 0; r < 4; ++r) {
      #pragma unroll
      for (int o = 1; o <= 8; o <<= 1) s[r] += __shfl_xor(s[r], o);
      inv[r] = 1.f / s[r];
    }
    #pragma unroll
    for (int kt = 0; kt < 13; ++kt)
      #pragma unroll
      for (int r = 0; r < 4; ++r)
        *(short*)(PB + ((g4 + r)*232 + kt*16 + col)*2) = f2bf(sc[kt][r]);
    #pragma unroll
    for (int r = 0; r < 4; ++r)
      *(short*)(PB + ((g4 + r)*232 + 208 + col)*2) = 0;
    asm volatile("s_waitcnt lgkmcnt(0)" ::: "memory");
    f32x4 o4[4];
    #pragma unroll
    for (int nt = 0; nt < 4; ++nt) { f32x4 z = {0.f,0.f,0.f,0.f}; o4[nt] = z; }
    #pragma unroll
    for (int kc = 0; kc < 7; ++kc) {
      bf16x8 pf = *(bf16x8*)(PB + col*464 + kc*64 + g*16);
      #pragma unroll
      for (int nt = 0; nt < 4; ++nt) {
        int d = nt*16 + col;
        int byte = (d*448 + kc*64 + g*16) ^ ((d & 7) << 4);
        bf16x8 vf = *(bf16x8*)(VtB + byte);
        o4[nt] = __builtin_amdgcn_mfma_f32_16x16x32_bf16(pf, vf, o4[nt], 0, 0, 0);
      }
    }
    #pragma unroll
    for (int nt = 0; nt < 4; ++nt)
      #pragma unroll
      for (int r = 0; r < 4; ++r) {
        int qr = qt*16 + g4 + r;
        if (qr < L_SEQ) base[(size_t)qr*384 + nt*16 + col] = f2bf(o4[nt][r] * inv[r]);
      }
  }
}

// out = feats + LN(nbr_agg + qn); feats precomputed (bf16), item/user bf16
__global__ __launch_bounds__(256) void final_kernel(
    const short* __restrict__ feats_b, const int* __restrict__ lsq, const int* __restrict__ nbr,
    const short* __restrict__ item_b, const short* __restrict__ user_b,
    const float* __restrict__ is_, const float* __restrict__ ib,
    float* __restrict__ out){
  int wave = threadIdx.x >> 6, lane = threadIdx.x & 63;
  size_t r = (size_t)blockIdx.x*4 + wave;
  ushort2 fv = ((const ushort2*)(feats_b + r*DIM))[lane];
  float fx = bf2f(fv.x), fy = bf2f(fv.y);

  int it = lsq[r];
  ushort2 qv = ((const ushort2*)(item_b + (size_t)it*DIM))[lane];
  float qx = bf2f(qv.x), qy = bf2f(qv.y);
  float knx[10], kny[10]; float scn[10];
  #pragma unroll
  for (int n = 0; n < 10; ++n) {
    int idx = nbr[r*10 + n];
    ushort2 kv = ((const ushort2*)(user_b + (size_t)idx*DIM))[lane];
    knx[n] = bf2f(kv.x); kny[n] = bf2f(kv.y);
    float p = wave_sum(qx*knx[n] + qy*kny[n]);
    scn[n] = idx ? p * 0.08838834764831845f : -1.0e9f;
  }
  float m = scn[0];
  #pragma unroll
  for (int n = 1; n < 10; ++n) m = fmaxf(m, scn[n]);
  float w[10], sum = 0.f;
  #pragma unroll
  for (int n = 0; n < 10; ++n) { w[n] = expf(scn[n] - m); sum += w[n]; }
  float invs = 1.f / sum;
  float ax = 0.f, ay = 0.f;
  #pragma unroll
  for (int n = 0; n < 10; ++n) { ax += w[n]*knx[n]; ay += w[n]*kny[n]; }
  ax = ax*invs + qx;
  ay = ay*invs + qy;
  float mu2 = wave_sum(ax + ay) * (1.f/DIM);
  float dx2 = ax - mu2, dy2 = ay - mu2;
  float var2 = wave_sum(dx2*dx2 + dy2*dy2) * (1.f/DIM);
  float inv2 = 1.f / sqrtf(var2 + 1e-8f);
  float2 isc = ((const float2*)is_)[lane], ibc = ((const float2*)ib)[lane];
  float2 o;
  o.x = fx + dx2*inv2*isc.x + ibc.x;
  o.y = fy + dy2*inv2*isc.y + ibc.y;
  ((float2*)(out + r*DIM))[lane] = o;
}

extern "C" void kernel_launch(void* const* d_in, const int* in_sizes, int n_in,
                              void* d_out, int out_size, void* d_ws, size_t ws_size,
                              hipStream_t stream) {
  const int*   lsq    = (const int*)d_in[0];
  const int*   nbr    = (const int*)d_in[1];
  const float* item   = (const float*)d_in[2];
  const float* user   = (const float*)d_in[3];
  const float* pos    = (const float*)d_in[4];
  const float* attn_s = (const float*)d_in[5];
  const float* attn_b = (const float*)d_in[6];
  const float* Wqkv   = (const float*)d_in[7];
  const float* bqkv   = (const float*)d_in[8];
  const float* Wo     = (const float*)d_in[9];
  const float* bo     = (const float*)d_in[10];
  const float* ffn_s  = (const float*)d_in[11];
  const float* ffn_b  = (const float*)d_in[12];
  const float* W1     = (const float*)d_in[13];
  const float* b1     = (const float*)d_in[14];
  const float* W2     = (const float*)d_in[15];
  const float* b2     = (const float*)d_in[16];
  const float* last_s = (const float*)d_in[17];
  const float* last_b = (const float*)d_in[18];
  const float* iui_s  = (const float*)d_in[19];
  const float* iui_b  = (const float*)d_in[20];
  float* out = (float*)d_out;

  const int N = NROWS;  // 51200 rows
  short* seqs_b = (short*)d_ws;                       // N x 128 bf16
  short* lnq_b  = seqs_b + (size_t)N*DIM;             // N x 128 bf16
  short* qkv_b  = lnq_b  + (size_t)N*DIM;             // N x 384 bf16
  short* item_b = qkv_b  + (size_t)N*384;             // 100001 x 128 bf16
  short* user_b = item_b + (size_t)100001*DIM;        // 50001 x 128 bf16
  short* wqkv_b = user_b + (size_t)50001*DIM;         // 2 x 384 x 128
  short* wo_b   = wqkv_b + 2*384*128;
  short* w1_b   = wo_b   + 2*128*128;
  short* w2_b   = w1_b   + 2*128*128;

  cvt4_kernel<<<(2*384*128/4+255)/256, 256, 0, stream>>>(Wqkv, wqkv_b, 2*384*128/4);
  cvt4_kernel<<<(2*128*128/4+255)/256, 256, 0, stream>>>(Wo,   wo_b,   2*128*128/4);
  cvt4_kernel<<<(2*128*128/4+255)/256, 256, 0, stream>>>(W1,   w1_b,   2*128*128/4);
  cvt4_kernel<<<(2*128*128/4+255)/256, 256, 0, stream>>>(W2,   w2_b,   2*128*128/4);
  cvt4_kernel<<<(100001*DIM/4+255)/256, 256, 0, stream>>>(item, item_b, 100001*DIM/4);
  cvt4_kernel<<<(50001*DIM/4+255)/256, 256, 0, stream>>>(user, user_b, 50001*DIM/4);

  embed_ln_kernel<<<N/4, 256, 0, stream>>>(lsq, item_b, pos, attn_s, attn_b, seqs_b, lnq_b);

  for (int i = 0; i < 2; ++i) {
    // fused QKV: x=0 -> Q from lnq (pre-scaled 1/8), x=1,2 -> K,V from seqs
    mgemm_kernel<0,0,0,0,1,1><<<dim3(3, N/128), 512, 0, stream>>>(
        lnq_b, seqs_b, 128, wqkv_b + (size_t)i*384*128, bqkv + i*384,
        qkv_b, 384, nullptr, nullptr, nullptr, nullptr, nullptr);
    attn_kernel<<<256*2, 512, 0, stream>>>(qkv_b);
    // Wo + residual(q=lnq) -> fused ffn_ln -> lnq_b (x). post-attn seqs not needed.
    mgemm_kernel<0,1,0,1,0,0><<<dim3(1, N/128), 512, 0, stream>>>(
        qkv_b, nullptr, 384, wo_b + (size_t)i*128*128, bo + i*DIM,
        nullptr, 128, lnq_b, nullptr, ffn_s + i*DIM, ffn_b + i*DIM, lnq_b);
    // FFN1 relu -> qkv_b scratch (ldc=128)
    mgemm_kernel<1,0,0,0,1,0><<<dim3(1, N/128), 512, 0, stream>>>(
        lnq_b, nullptr, 128, w1_b + (size_t)i*128*128, b1 + i*DIM,
        qkv_b, 128, nullptr, nullptr, nullptr, nullptr, nullptr);
    // FFN2 + residual(x=lnq) + mask -> fused next-LN
    if (i == 0) {
      // -> seqs_b (for next layer K/V) and lnq_b = LN1 of layer 1
      mgemm_kernel<0,1,1,1,1,0><<<dim3(1, N/128), 512, 0, stream>>>(
          qkv_b, nullptr, 128, w2_b, b2,
          seqs_b, 128, lnq_b, lsq, attn_s + DIM, attn_b + DIM, lnq_b);
    } else {
      // -> lnq_b = last_ln(seqs) = feats (seqs itself no longer needed)
      mgemm_kernel<0,1,1,1,0,0><<<dim3(1, N/128), 512, 0, stream>>>(
          qkv_b, nullptr, 128, w2_b + (size_t)128*128, b2 + DIM,
          nullptr, 128, lnq_b, lsq, last_s, last_b, lnq_b);
    }
  }

  final_kernel<<<N/4, 256, 0, stream>>>(lnq_b, lsq, nbr, item_b, user_b,
                                        iui_s, iui_b, out);
}

// Round 6
// 227.500 us; speedup vs baseline: 5.4139x; 1.1229x over previous
//
#include <hip/hip_runtime.h>
#include <hip/hip_bf16.h>

#define L_SEQ 200
#define DIM 128
#define NROWS (256*200)

typedef __attribute__((ext_vector_type(8))) short bf16x8;
typedef __attribute__((ext_vector_type(4))) float f32x4;

__device__ __forceinline__ float wave_sum(float v){
  #pragma unroll
  for (int o = 32; o; o >>= 1) v += __shfl_xor(v, o);
  return v;
}
__device__ __forceinline__ short f2bf(float f){
  union { float f; unsigned u; } x; x.f = f;
  unsigned r = x.u + 0x7fffu + ((x.u >> 16) & 1u);
  return (short)(r >> 16);
}
__device__ __forceinline__ float bf2f(unsigned short u){
  union { unsigned u; float f; } x; x.u = ((unsigned)u) << 16;
  return x.f;
}

// fp32 -> bf16, 4 at a time (weights only)
__global__ void cvt4_kernel(const float* __restrict__ src, short* __restrict__ dst, int n4){
  int i = blockIdx.x*256 + threadIdx.x;
  if (i < n4) {
    float4 v = ((const float4*)src)[i];
    short4 s; s.x = f2bf(v.x); s.y = f2bf(v.y); s.z = f2bf(v.z); s.w = f2bf(v.w);
    ((short4*)dst)[i] = s;
  }
}

// seqs = item[log_seqs]*sqrt(D)+pos (masked); lnq = LN(seqs, attn_ln0). bf16 out.
__global__ __launch_bounds__(256) void embed_ln_kernel(
    const int* __restrict__ lsq, const float* __restrict__ item,
    const float* __restrict__ pos, const float* __restrict__ s, const float* __restrict__ b,
    short* __restrict__ seqs_b, short* __restrict__ lnq_b){
  int wave = threadIdx.x >> 6, lane = threadIdx.x & 63;
  size_t r = (size_t)blockIdx.x*4 + wave;
  int it = lsq[r];
  float2 iv = ((const float2*)(item + (size_t)it*DIM))[lane];
  float2 p = ((const float2*)(pos + (r % L_SEQ)*DIM))[lane];
  float vx = 0.f, vy = 0.f;
  if (it) {
    vx = iv.x * 11.313708498984761f + p.x;
    vy = iv.y * 11.313708498984761f + p.y;
  }
  short2 sv; sv.x = f2bf(vx); sv.y = f2bf(vy);
  ((short2*)(seqs_b + r*DIM))[lane] = sv;
  float mu = wave_sum(vx + vy) * (1.f/DIM);
  float dx = vx - mu, dy = vy - mu;
  float var = wave_sum(dx*dx + dy*dy) * (1.f/DIM);
  float inv = 1.f / sqrtf(var + 1e-8f);
  float2 sc = ((const float2*)s)[lane];
  float2 bc = ((const float2*)b)[lane];
  short2 ov; ov.x = f2bf(dx*inv*sc.x + bc.x); ov.y = f2bf(dy*inv*sc.y + bc.y);
  ((short2*)(lnq_b + r*DIM))[lane] = ov;
}

#define MLP_MFMA(accv) do { \
  _Pragma("unroll") \
  for (int kc = 0; kc < 4; ++kc) { \
    bf16x8 af[4], bfr[2]; \
    _Pragma("unroll") \
    for (int mf = 0; mf < 4; ++mf) { \
      int rr = mbase + mf*16 + col; \
      int byt = (rr*256 + kc*64 + g*16) ^ ((rr & 7) << 4); \
      af[mf] = *(bf16x8*)(AsB + byt); \
    } \
    _Pragma("unroll") \
    for (int nf = 0; nf < 2; ++nf) { \
      int rr = nbase + nf*16 + col; \
      int byt = (rr*256 + kc*64 + g*16) ^ ((rr & 7) << 4); \
      bfr[nf] = *(bf16x8*)(BsB + byt); \
    } \
    _Pragma("unroll") \
    for (int mf = 0; mf < 4; ++mf) \
      _Pragma("unroll") \
      for (int nf = 0; nf < 2; ++nf) \
        accv[mf][nf] = __builtin_amdgcn_mfma_f32_16x16x32_bf16(af[mf], bfr[nf], accv[mf][nf], 0, 0, 0); \
  } \
} while(0)

#define LN_REDUCE(accv) do { \
  _Pragma("unroll") \
  for (int mf = 0; mf < 4; ++mf) { \
    _Pragma("unroll") \
    for (int r = 0; r < 4; ++r) { \
      float s1 = accv[mf][0][r] + accv[mf][1][r]; \
      float s2 = accv[mf][0][r]*accv[mf][0][r] + accv[mf][1][r]*accv[mf][1][r]; \
      _Pragma("unroll") \
      for (int o = 1; o <= 8; o <<= 1) { s1 += __shfl_xor(s1, o); s2 += __shfl_xor(s2, o); } \
      if (col == 0) { int rL = mbase + mf*16 + g*4 + r; redP[0][wn][rL] = s1; redP[1][wn][rL] = s2; } \
    } \
  } \
  __syncthreads(); \
  if (t < 128) { \
    float s1 = redP[0][0][t] + redP[0][1][t] + redP[0][2][t] + redP[0][3][t]; \
    float s2 = redP[1][0][t] + redP[1][1][t] + redP[1][2][t] + redP[1][3][t]; \
    float mu_ = s1 * (1.f/DIM); \
    float var_ = s2 * (1.f/DIM) - mu_*mu_; \
    muA[t] = mu_; invA[t] = 1.f / sqrtf(var_ + 1e-8f); \
  } \
  __syncthreads(); \
} while(0)

// QKV projection: grid (3, N/128). x==0 -> Q from lnq (scaled 1/8), x=1,2 -> K,V from seqs.
__global__ __launch_bounds__(512) void qkv_kernel(
    const short* __restrict__ lnq, const short* __restrict__ seqs,
    const short* __restrict__ Wb, const float* __restrict__ bias,
    short* __restrict__ C){
  __shared__ short As[16384];
  __shared__ short Bs[16384];
  char* AsB = (char*)As; char* BsB = (char*)Bs;
  const int row0 = blockIdx.y * 128, col0 = blockIdx.x * 128;
  const int t = threadIdx.x;
  const short* Ap = (blockIdx.x == 0) ? lnq : seqs;

  #pragma unroll
  for (int i = 0; i < 4; ++i) {
    int flat = t*8 + i*4096;
    int rr = flat >> 7, cc = flat & 127;
    bf16x8 a8 = *(const bf16x8*)(Ap + (size_t)(row0 + rr)*128 + cc);
    int byt = (rr*256 + cc*2) ^ ((rr & 7) << 4);
    *(bf16x8*)(AsB + byt) = a8;
    bf16x8 b8 = *(const bf16x8*)(Wb + (size_t)(col0 + rr)*128 + cc);
    *(bf16x8*)(BsB + byt) = b8;
  }
  __syncthreads();

  const int w = t >> 6, l = t & 63;
  const int wm = w >> 2, wn = w & 3;
  const int col = l & 15, g = l >> 4;
  const int mbase = wm*64, nbase = wn*32;

  f32x4 acc[4][2];
  #pragma unroll
  for (int mf = 0; mf < 4; ++mf)
    #pragma unroll
    for (int nf = 0; nf < 2; ++nf) { f32x4 z = {0.f,0.f,0.f,0.f}; acc[mf][nf] = z; }
  MLP_MFMA(acc);

  float biasv[2];
  #pragma unroll
  for (int nf = 0; nf < 2; ++nf) biasv[nf] = bias[col0 + nbase + nf*16 + col];
  const float qs = (blockIdx.x == 0) ? 0.125f : 1.f;
  #pragma unroll
  for (int mf = 0; mf < 4; ++mf)
    #pragma unroll
    for (int r = 0; r < 4; ++r) {
      int rr = row0 + mbase + mf*16 + g*4 + r;
      #pragma unroll
      for (int nf = 0; nf < 2; ++nf) {
        int cc = col0 + nbase + nf*16 + col;
        float v = (acc[mf][nf][r] + biasv[nf]) * qs;
        C[(size_t)rr*384 + cc] = f2bf(v);
      }
    }
}

// Fused per-layer MLP block: attnout@Wo+bo+resq -> LN(ffn) -> relu(@W1+b1) -> @W2+b2+x
// -> mask -> (optional C=seqs_next) + LN(lnS2) -> lnOut. One block per 128 rows.
template<int WRITE_C>
__global__ __launch_bounds__(512) void mlp_kernel(
    const short* __restrict__ qkvQ, const short* __restrict__ resq,
    const short* __restrict__ wo_b, const float* __restrict__ bo,
    const float* __restrict__ ffnS, const float* __restrict__ ffnB,
    const short* __restrict__ w1_b, const float* __restrict__ b1,
    const short* __restrict__ w2_b, const float* __restrict__ b2,
    const int* __restrict__ lsq,
    short* __restrict__ C,
    const float* __restrict__ lnS2, const float* __restrict__ lnB2,
    short* __restrict__ lnOut){
  __shared__ short As[16384];
  __shared__ short Bs[16384];
  __shared__ float redP[2][4][128];
  __shared__ float muA[128], invA[128];
  char* AsB = (char*)As; char* BsB = (char*)Bs;
  const int row0 = blockIdx.x * 128;
  const int t = threadIdx.x;

  // stage attn-out tile (lda 384) and Wo
  #pragma unroll
  for (int i = 0; i < 4; ++i) {
    int flat = t*8 + i*4096;
    int rr = flat >> 7, cc = flat & 127;
    bf16x8 a8 = *(const bf16x8*)(qkvQ + (size_t)(row0 + rr)*384 + cc);
    int byt = (rr*256 + cc*2) ^ ((rr & 7) << 4);
    *(bf16x8*)(AsB + byt) = a8;
    bf16x8 b8 = *(const bf16x8*)(wo_b + (size_t)rr*128 + cc);
    *(bf16x8*)(BsB + byt) = b8;
  }
  __syncthreads();

  const int w = t >> 6, l = t & 63;
  const int wm = w >> 2, wn = w & 3;
  const int col = l & 15, g = l >> 4;
  const int mbase = wm*64, nbase = wn*32;

  f32x4 acc[4][2];
  #pragma unroll
  for (int mf = 0; mf < 4; ++mf)
    #pragma unroll
    for (int nf = 0; nf < 2; ++nf) { f32x4 z = {0.f,0.f,0.f,0.f}; acc[mf][nf] = z; }
  MLP_MFMA(acc);

  // t = acc + bo + resq (pre-FFN seqs)
  float bov[2];
  #pragma unroll
  for (int nf = 0; nf < 2; ++nf) bov[nf] = bo[nbase + nf*16 + col];
  #pragma unroll
  for (int mf = 0; mf < 4; ++mf)
    #pragma unroll
    for (int r = 0; r < 4; ++r) {
      int rL = mbase + mf*16 + g*4 + r;
      #pragma unroll
      for (int nf = 0; nf < 2; ++nf) {
        int cL = nbase + nf*16 + col;
        acc[mf][nf][r] += bov[nf] + bf2f(((const unsigned short*)resq)[(size_t)(row0 + rL)*DIM + cL]);
      }
    }
  LN_REDUCE(acc);

  // x = LN(t); keep f32 in regs, bf16 copy into As for stage 2
  float xv[4][2][4];
  #pragma unroll
  for (int mf = 0; mf < 4; ++mf)
    #pragma unroll
    for (int r = 0; r < 4; ++r) {
      int rL = mbase + mf*16 + g*4 + r;
      float mu = muA[rL], inv = invA[rL];
      #pragma unroll
      for (int nf = 0; nf < 2; ++nf) {
        int cL = nbase + nf*16 + col;
        float lnv = (acc[mf][nf][r] - mu)*inv*ffnS[cL] + ffnB[cL];
        xv[mf][nf][r] = lnv;
        int byt = (rL*256 + cL*2) ^ ((rL & 7) << 4);
        *(short*)(AsB + byt) = f2bf(lnv);
      }
    }
  // stage W1
  #pragma unroll
  for (int i = 0; i < 4; ++i) {
    int flat = t*8 + i*4096;
    int rr = flat >> 7, cc = flat & 127;
    bf16x8 b8 = *(const bf16x8*)(w1_b + (size_t)rr*128 + cc);
    int byt = (rr*256 + cc*2) ^ ((rr & 7) << 4);
    *(bf16x8*)(BsB + byt) = b8;
  }
  __syncthreads();

  #pragma unroll
  for (int mf = 0; mf < 4; ++mf)
    #pragma unroll
    for (int nf = 0; nf < 2; ++nf) { f32x4 z = {0.f,0.f,0.f,0.f}; acc[mf][nf] = z; }
  MLP_MFMA(acc);
  __syncthreads();   // all As/Bs reads done before overwrite

  // h = relu(acc + b1) -> As; stage W2 -> Bs
  float b1v[2];
  #pragma unroll
  for (int nf = 0; nf < 2; ++nf) b1v[nf] = b1[nbase + nf*16 + col];
  #pragma unroll
  for (int mf = 0; mf < 4; ++mf)
    #pragma unroll
    for (int r = 0; r < 4; ++r) {
      int rL = mbase + mf*16 + g*4 + r;
      #pragma unroll
      for (int nf = 0; nf < 2; ++nf) {
        int cL = nbase + nf*16 + col;
        float h = fmaxf(acc[mf][nf][r] + b1v[nf], 0.f);
        int byt = (rL*256 + cL*2) ^ ((rL & 7) << 4);
        *(short*)(AsB + byt) = f2bf(h);
      }
    }
  #pragma unroll
  for (int i = 0; i < 4; ++i) {
    int flat = t*8 + i*4096;
    int rr = flat >> 7, cc = flat & 127;
    bf16x8 b8 = *(const bf16x8*)(w2_b + (size_t)rr*128 + cc);
    int byt = (rr*256 + cc*2) ^ ((rr & 7) << 4);
    *(bf16x8*)(BsB + byt) = b8;
  }
  __syncthreads();

  #pragma unroll
  for (int mf = 0; mf < 4; ++mf)
    #pragma unroll
    for (int nf = 0; nf < 2; ++nf) { f32x4 z = {0.f,0.f,0.f,0.f}; acc[mf][nf] = z; }
  MLP_MFMA(acc);

  // v = acc + b2 + x, masked
  float b2v[2];
  #pragma unroll
  for (int nf = 0; nf < 2; ++nf) b2v[nf] = b2[nbase + nf*16 + col];
  #pragma unroll
  for (int mf = 0; mf < 4; ++mf)
    #pragma unroll
    for (int r = 0; r < 4; ++r) {
      int rL = mbase + mf*16 + g*4 + r;
      bool zr = (lsq[row0 + rL] == 0);
      #pragma unroll
      for (int nf = 0; nf < 2; ++nf) {
        float v = acc[mf][nf][r] + b2v[nf] + xv[mf][nf][r];
        if (zr) v = 0.f;
        acc[mf][nf][r] = v;
      }
    }
  LN_REDUCE(acc);
  #pragma unroll
  for (int mf = 0; mf < 4; ++mf)
    #pragma unroll
    for (int r = 0; r < 4; ++r) {
      int rL = mbase + mf*16 + g*4 + r;
      float mu = muA[rL], inv = invA[rL];
      #pragma unroll
      for (int nf = 0; nf < 2; ++nf) {
        int cL = nbase + nf*16 + col;
        float v = acc[mf][nf][r];
        float lnv = (v - mu)*inv*lnS2[cL] + lnB2[cL];
        lnOut[(size_t)(row0 + rL)*DIM + cL] = f2bf(lnv);
        if (WRITE_C) C[(size_t)(row0 + rL)*DIM + cL] = f2bf(v);
      }
    }
}

// MFMA causal attention, bf16 qkv, causal tile-skip. Out overwrites Q slot.
__global__ __launch_bounds__(512) void attn_kernel(short* __restrict__ qkv){
  __shared__ short Ks[224*64];
  __shared__ short Vt[64*224];
  __shared__ short Ps[8][16*232];
  const int b = blockIdx.x >> 1, h = blockIdx.x & 1;
  short* base = qkv + (size_t)b*L_SEQ*384 + h*64;
  const short* baseK = base + 128;
  const short* baseV = base + 256;
  const int t = threadIdx.x;
  char* KsB = (char*)Ks;
  char* VtB = (char*)Vt;

  for (int idx = t; idx < 224*8; idx += 512) {
    int row = idx >> 3, c8 = idx & 7;
    bf16x8 kv = {0,0,0,0,0,0,0,0}, vv = {0,0,0,0,0,0,0,0};
    if (row < L_SEQ) {
      kv = *(const bf16x8*)(baseK + (size_t)row*384 + c8*8);
      vv = *(const bf16x8*)(baseV + (size_t)row*384 + c8*8);
    }
    int kbyte = (row*128 + c8*16) ^ ((row & 7) << 4);
    *(bf16x8*)(KsB + kbyte) = kv;
    #pragma unroll
    for (int e = 0; e < 8; ++e) {
      int d = c8*8 + e;
      int vbyte = (d*448 + row*2) ^ ((d & 7) << 4);
      *(short*)(VtB + vbyte) = vv[e];
    }
  }
  __syncthreads();

  const int w = t >> 6, l = t & 63;
  const int col = l & 15, g = l >> 4, g4 = g * 4;
  char* PB = (char*)Ps[w];

  const int ntiles = (w < 5) ? 2 : 1;
  for (int j = 0; j < ntiles; ++j) {
    const int qt = w + 8*j;
    bf16x8 qf[2];
    {
      int gr = qt*16 + col;
      #pragma unroll
      for (int c = 0; c < 2; ++c) {
        bf16x8 q = {0,0,0,0,0,0,0,0};
        if (gr < L_SEQ) q = *(const bf16x8*)(base + (size_t)gr*384 + c*32 + g*8);
        qf[c] = q;
      }
    }
    f32x4 sc[13];
    #pragma unroll
    for (int kt = 0; kt < 13; ++kt) {
      if (kt <= qt) {
        f32x4 a = {0.f,0.f,0.f,0.f};
        #pragma unroll
        for (int c = 0; c < 2; ++c) {
          int row = kt*16 + col;
          int byt = (row*128 + c*64 + g*16) ^ ((row & 7) << 4);
          bf16x8 kf = *(bf16x8*)(KsB + byt);
          a = __builtin_amdgcn_mfma_f32_16x16x32_bf16(qf[c], kf, a, 0, 0, 0);
        }
        sc[kt] = a;
      }
    }
    float m[4] = {-1e30f,-1e30f,-1e30f,-1e30f};
    #pragma unroll
    for (int kt = 0; kt < 13; ++kt) {
      if (kt <= qt) {
        #pragma unroll
        for (int r = 0; r < 4; ++r) {
          bool ok = (kt < qt) || (col <= g4 + r);
          if (!ok) sc[kt][r] = -1e30f;
          m[r] = fmaxf(m[r], sc[kt][r]);
        }
      }
    }
    #pragma unroll
    for (int r = 0; r < 4; ++r) {
      #pragma unroll
      for (int o = 1; o <= 8; o <<= 1) m[r] = fmaxf(m[r], __shfl_xor(m[r], o));
    }
    float s[4] = {0.f,0.f,0.f,0.f};
    #pragma unroll
    for (int kt = 0; kt < 13; ++kt) {
      if (kt <= qt) {
        #pragma unroll
        for (int r = 0; r < 4; ++r) {
          float e = __expf(sc[kt][r] - m[r]);
          sc[kt][r] = e;
          s[r] += e;
        }
      }
    }
    float inv[4];
    #pragma unroll
    for (int r = 0; r < 4; ++r) {
      #pragma unroll
      for (int o = 1; o <= 8; o <<= 1) s[r] += __shfl_xor(s[r], o);
      inv[r] = 1.f / s[r];
    }
    #pragma unroll
    for (int kt = 0; kt < 13; ++kt) {
      if (kt <= qt) {
        #pragma unroll
        for (int r = 0; r < 4; ++r)
          *(short*)(PB + ((g4 + r)*232 + kt*16 + col)*2) = f2bf(sc[kt][r]);
      } else if (kt == qt + 1) {
        #pragma unroll
        for (int r = 0; r < 4; ++r)
          *(short*)(PB + ((g4 + r)*232 + kt*16 + col)*2) = 0;
      }
    }
    #pragma unroll
    for (int r = 0; r < 4; ++r)
      *(short*)(PB + ((g4 + r)*232 + 208 + col)*2) = 0;
    asm volatile("s_waitcnt lgkmcnt(0)" ::: "memory");
    f32x4 o4[4];
    #pragma unroll
    for (int nt = 0; nt < 4; ++nt) { f32x4 z = {0.f,0.f,0.f,0.f}; o4[nt] = z; }
    const int kcmax = (qt*16 + 15) >> 5;
    #pragma unroll
    for (int kc = 0; kc < 7; ++kc) {
      if (kc <= kcmax) {
        bf16x8 pf = *(bf16x8*)(PB + col*464 + kc*64 + g*16);
        #pragma unroll
        for (int nt = 0; nt < 4; ++nt) {
          int d = nt*16 + col;
          int byt = (d*448 + kc*64 + g*16) ^ ((d & 7) << 4);
          bf16x8 vf = *(bf16x8*)(VtB + byt);
          o4[nt] = __builtin_amdgcn_mfma_f32_16x16x32_bf16(pf, vf, o4[nt], 0, 0, 0);
        }
      }
    }
    #pragma unroll
    for (int nt = 0; nt < 4; ++nt)
      #pragma unroll
      for (int r = 0; r < 4; ++r) {
        int qr = qt*16 + g4 + r;
        if (qr < L_SEQ) base[(size_t)qr*384 + nt*16 + col] = f2bf(o4[nt][r] * inv[r]);
      }
  }
}

// out = feats + LN(nbr_agg + qn); feats bf16, item/user fp32 gathers
__global__ __launch_bounds__(256) void final_kernel(
    const short* __restrict__ feats_b, const int* __restrict__ lsq, const int* __restrict__ nbr,
    const float* __restrict__ item, const float* __restrict__ user,
    const float* __restrict__ is_, const float* __restrict__ ib,
    float* __restrict__ out){
  int wave = threadIdx.x >> 6, lane = threadIdx.x & 63;
  size_t r = (size_t)blockIdx.x*4 + wave;
  ushort2 fv = ((const ushort2*)(feats_b + r*DIM))[lane];
  float fx = bf2f(fv.x), fy = bf2f(fv.y);

  int it = lsq[r];
  float2 qv = ((const float2*)(item + (size_t)it*DIM))[lane];
  float qx = qv.x, qy = qv.y;
  float knx[10], kny[10]; float scn[10];
  #pragma unroll
  for (int n = 0; n < 10; ++n) {
    int idx = nbr[r*10 + n];
    float2 kv = ((const float2*)(user + (size_t)idx*DIM))[lane];
    knx[n] = kv.x; kny[n] = kv.y;
    float p = wave_sum(qx*knx[n] + qy*kny[n]);
    scn[n] = idx ? p * 0.08838834764831845f : -1.0e9f;
  }
  float m = scn[0];
  #pragma unroll
  for (int n = 1; n < 10; ++n) m = fmaxf(m, scn[n]);
  float w[10], sum = 0.f;
  #pragma unroll
  for (int n = 0; n < 10; ++n) { w[n] = expf(scn[n] - m); sum += w[n]; }
  float invs = 1.f / sum;
  float ax = 0.f, ay = 0.f;
  #pragma unroll
  for (int n = 0; n < 10; ++n) { ax += w[n]*knx[n]; ay += w[n]*kny[n]; }
  ax = ax*invs + qx;
  ay = ay*invs + qy;
  float mu2 = wave_sum(ax + ay) * (1.f/DIM);
  float dx2 = ax - mu2, dy2 = ay - mu2;
  float var2 = wave_sum(dx2*dx2 + dy2*dy2) * (1.f/DIM);
  float inv2 = 1.f / sqrtf(var2 + 1e-8f);
  float2 isc = ((const float2*)is_)[lane], ibc = ((const float2*)ib)[lane];
  float2 o;
  o.x = fx + dx2*inv2*isc.x + ibc.x;
  o.y = fy + dy2*inv2*isc.y + ibc.y;
  ((float2*)(out + r*DIM))[lane] = o;
}

extern "C" void kernel_launch(void* const* d_in, const int* in_sizes, int n_in,
                              void* d_out, int out_size, void* d_ws, size_t ws_size,
                              hipStream_t stream) {
  const int*   lsq    = (const int*)d_in[0];
  const int*   nbr    = (const int*)d_in[1];
  const float* item   = (const float*)d_in[2];
  const float* user   = (const float*)d_in[3];
  const float* pos    = (const float*)d_in[4];
  const float* attn_s = (const float*)d_in[5];
  const float* attn_b = (const float*)d_in[6];
  const float* Wqkv   = (const float*)d_in[7];
  const float* bqkv   = (const float*)d_in[8];
  const float* Wo     = (const float*)d_in[9];
  const float* bo     = (const float*)d_in[10];
  const float* ffn_s  = (const float*)d_in[11];
  const float* ffn_b  = (const float*)d_in[12];
  const float* W1     = (const float*)d_in[13];
  const float* b1     = (const float*)d_in[14];
  const float* W2     = (const float*)d_in[15];
  const float* b2     = (const float*)d_in[16];
  const float* last_s = (const float*)d_in[17];
  const float* last_b = (const float*)d_in[18];
  const float* iui_s  = (const float*)d_in[19];
  const float* iui_b  = (const float*)d_in[20];
  float* out = (float*)d_out;

  const int N = NROWS;  // 51200 rows
  short* seqs_b = (short*)d_ws;                       // N x 128 bf16
  short* lnq_b  = seqs_b + (size_t)N*DIM;             // N x 128 bf16
  short* qkv_b  = lnq_b  + (size_t)N*DIM;             // N x 384 bf16
  short* wqkv_b = qkv_b  + (size_t)N*384;             // 2 x 384 x 128
  short* wo_b   = wqkv_b + 2*384*128;
  short* w1_b   = wo_b   + 2*128*128;
  short* w2_b   = w1_b   + 2*128*128;

  cvt4_kernel<<<(2*384*128/4+255)/256, 256, 0, stream>>>(Wqkv, wqkv_b, 2*384*128/4);
  cvt4_kernel<<<(2*128*128/4+255)/256, 256, 0, stream>>>(Wo,   wo_b,   2*128*128/4);
  cvt4_kernel<<<(2*128*128/4+255)/256, 256, 0, stream>>>(W1,   w1_b,   2*128*128/4);
  cvt4_kernel<<<(2*128*128/4+255)/256, 256, 0, stream>>>(W2,   w2_b,   2*128*128/4);

  embed_ln_kernel<<<N/4, 256, 0, stream>>>(lsq, item, pos, attn_s, attn_b, seqs_b, lnq_b);

  for (int i = 0; i < 2; ++i) {
    qkv_kernel<<<dim3(3, N/128), 512, 0, stream>>>(
        lnq_b, seqs_b, wqkv_b + (size_t)i*384*128, bqkv + i*384, qkv_b);
    attn_kernel<<<256*2, 512, 0, stream>>>(qkv_b);
    if (i == 0) {
      // -> seqs_b (layer-1 K/V input) and lnq_b = layer-1 attn LN
      mlp_kernel<1><<<N/128, 512, 0, stream>>>(
          qkv_b, lnq_b, wo_b, bo, ffn_s, ffn_b,
          w1_b, b1, w2_b, b2, lsq,
          seqs_b, attn_s + DIM, attn_b + DIM, lnq_b);
    } else {
      // -> lnq_b = last_ln(seqs) = feats
      mlp_kernel<0><<<N/128, 512, 0, stream>>>(
          qkv_b, lnq_b, wo_b + 128*128, bo + DIM, ffn_s + DIM, ffn_b + DIM,
          w1_b + 128*128, b1 + DIM, w2_b + 128*128, b2 + DIM, lsq,
          nullptr, last_s, last_b, lnq_b);
    }
  }

  final_kernel<<<N/4, 256, 0, stream>>>(lnq_b, lsq, nbr, item, user,
                                        iui_s, iui_b, out);
}

// Round 7
// 223.287 us; speedup vs baseline: 5.5160x; 1.0189x over previous
//
#include <hip/hip_runtime.h>
#include <hip/hip_bf16.h>

#define L_SEQ 200
#define DIM 128
#define NROWS (256*200)

typedef __attribute__((ext_vector_type(8))) short bf16x8;
typedef __attribute__((ext_vector_type(4))) float f32x4;

__device__ __forceinline__ float wave_sum(float v){
  #pragma unroll
  for (int o = 32; o; o >>= 1) v += __shfl_xor(v, o);
  return v;
}
__device__ __forceinline__ short f2bf(float f){
  union { float f; unsigned u; } x; x.f = f;
  unsigned r = x.u + 0x7fffu + ((x.u >> 16) & 1u);
  return (short)(r >> 16);
}
__device__ __forceinline__ float bf2f(unsigned short u){
  union { unsigned u; float f; } x; x.u = ((unsigned)u) << 16;
  return x.f;
}

// all four bf16 weight arrays in one launch (dst arrays are contiguous)
__global__ void cvt_all_kernel(const float* __restrict__ Wqkv, const float* __restrict__ Wo,
                               const float* __restrict__ W1, const float* __restrict__ W2,
                               short* __restrict__ dst){
  int i = blockIdx.x*256 + threadIdx.x;   // float4 index, total 49152
  if (i >= 49152) return;
  const float* src; int off;
  if (i < 24576)      { src = Wqkv; off = i; }
  else if (i < 32768) { src = Wo;   off = i - 24576; }
  else if (i < 40960) { src = W1;   off = i - 32768; }
  else                { src = W2;   off = i - 40960; }
  float4 v = ((const float4*)src)[off];
  short4 s; s.x = f2bf(v.x); s.y = f2bf(v.y); s.z = f2bf(v.z); s.w = f2bf(v.w);
  ((short4*)dst)[i] = s;
}

// seqs = item[log_seqs]*sqrt(D)+pos (masked); lnq = LN(seqs, attn_ln0). bf16 out.
__global__ __launch_bounds__(256) void embed_ln_kernel(
    const int* __restrict__ lsq, const float* __restrict__ item,
    const float* __restrict__ pos, const float* __restrict__ s, const float* __restrict__ b,
    short* __restrict__ seqs_b, short* __restrict__ lnq_b){
  int wave = threadIdx.x >> 6, lane = threadIdx.x & 63;
  size_t r = (size_t)blockIdx.x*4 + wave;
  int it = lsq[r];
  float2 iv = ((const float2*)(item + (size_t)it*DIM))[lane];
  float2 p = ((const float2*)(pos + (r % L_SEQ)*DIM))[lane];
  float vx = 0.f, vy = 0.f;
  if (it) {
    vx = iv.x * 11.313708498984761f + p.x;
    vy = iv.y * 11.313708498984761f + p.y;
  }
  short2 sv; sv.x = f2bf(vx); sv.y = f2bf(vy);
  ((short2*)(seqs_b + r*DIM))[lane] = sv;
  float mu = wave_sum(vx + vy) * (1.f/DIM);
  float dx = vx - mu, dy = vy - mu;
  float var = wave_sum(dx*dx + dy*dy) * (1.f/DIM);
  float inv = 1.f / sqrtf(var + 1e-8f);
  float2 sc = ((const float2*)s)[lane];
  float2 bc = ((const float2*)b)[lane];
  short2 ov; ov.x = f2bf(dx*inv*sc.x + bc.x); ov.y = f2bf(dy*inv*sc.y + bc.y);
  ((short2*)(lnq_b + r*DIM))[lane] = ov;
}

#define MLP_MFMA(accv) do { \
  _Pragma("unroll") \
  for (int kc = 0; kc < 4; ++kc) { \
    bf16x8 af[4], bfr[2]; \
    _Pragma("unroll") \
    for (int mf = 0; mf < 4; ++mf) { \
      int rr = mbase + mf*16 + col; \
      int byt = (rr*256 + kc*64 + g*16) ^ ((rr & 7) << 4); \
      af[mf] = *(bf16x8*)(AsB + byt); \
    } \
    _Pragma("unroll") \
    for (int nf = 0; nf < 2; ++nf) { \
      int rr = nbase + nf*16 + col; \
      int byt = (rr*256 + kc*64 + g*16) ^ ((rr & 7) << 4); \
      bfr[nf] = *(bf16x8*)(BsB + byt); \
    } \
    _Pragma("unroll") \
    for (int mf = 0; mf < 4; ++mf) \
      _Pragma("unroll") \
      for (int nf = 0; nf < 2; ++nf) \
        accv[mf][nf] = __builtin_amdgcn_mfma_f32_16x16x32_bf16(af[mf], bfr[nf], accv[mf][nf], 0, 0, 0); \
  } \
} while(0)

#define LN_REDUCE(accv) do { \
  _Pragma("unroll") \
  for (int mf = 0; mf < 4; ++mf) { \
    _Pragma("unroll") \
    for (int r = 0; r < 4; ++r) { \
      float s1 = accv[mf][0][r] + accv[mf][1][r]; \
      float s2 = accv[mf][0][r]*accv[mf][0][r] + accv[mf][1][r]*accv[mf][1][r]; \
      _Pragma("unroll") \
      for (int o = 1; o <= 8; o <<= 1) { s1 += __shfl_xor(s1, o); s2 += __shfl_xor(s2, o); } \
      if (col == 0) { int rL = mbase + mf*16 + g*4 + r; redP[0][wn][rL] = s1; redP[1][wn][rL] = s2; } \
    } \
  } \
  __syncthreads(); \
  if (t < 128) { \
    float s1 = redP[0][0][t] + redP[0][1][t] + redP[0][2][t] + redP[0][3][t]; \
    float s2 = redP[1][0][t] + redP[1][1][t] + redP[1][2][t] + redP[1][3][t]; \
    float mu_ = s1 * (1.f/DIM); \
    float var_ = s2 * (1.f/DIM) - mu_*mu_; \
    muA[t] = mu_; invA[t] = 1.f / sqrtf(var_ + 1e-8f); \
  } \
  __syncthreads(); \
} while(0)

// QKV projection: grid (3, N/128). x==0 -> Q from lnq (scaled 1/8), x=1,2 -> K,V from seqs.
__global__ __launch_bounds__(512) void qkv_kernel(
    const short* __restrict__ lnq, const short* __restrict__ seqs,
    const short* __restrict__ Wb, const float* __restrict__ bias,
    short* __restrict__ C){
  __shared__ short As[16384];
  __shared__ short Bs[16384];
  char* AsB = (char*)As; char* BsB = (char*)Bs;
  const int row0 = blockIdx.y * 128, col0 = blockIdx.x * 128;
  const int t = threadIdx.x;
  const short* Ap = (blockIdx.x == 0) ? lnq : seqs;

  #pragma unroll
  for (int i = 0; i < 4; ++i) {
    int flat = t*8 + i*4096;
    int rr = flat >> 7, cc = flat & 127;
    bf16x8 a8 = *(const bf16x8*)(Ap + (size_t)(row0 + rr)*128 + cc);
    int byt = (rr*256 + cc*2) ^ ((rr & 7) << 4);
    *(bf16x8*)(AsB + byt) = a8;
    bf16x8 b8 = *(const bf16x8*)(Wb + (size_t)(col0 + rr)*128 + cc);
    *(bf16x8*)(BsB + byt) = b8;
  }
  __syncthreads();

  const int w = t >> 6, l = t & 63;
  const int wm = w >> 2, wn = w & 3;
  const int col = l & 15, g = l >> 4;
  const int mbase = wm*64, nbase = wn*32;

  f32x4 acc[4][2];
  #pragma unroll
  for (int mf = 0; mf < 4; ++mf)
    #pragma unroll
    for (int nf = 0; nf < 2; ++nf) { f32x4 z = {0.f,0.f,0.f,0.f}; acc[mf][nf] = z; }
  MLP_MFMA(acc);

  float biasv[2];
  #pragma unroll
  for (int nf = 0; nf < 2; ++nf) biasv[nf] = bias[col0 + nbase + nf*16 + col];
  const float qs = (blockIdx.x == 0) ? 0.125f : 1.f;
  #pragma unroll
  for (int mf = 0; mf < 4; ++mf)
    #pragma unroll
    for (int r = 0; r < 4; ++r) {
      int rr = row0 + mbase + mf*16 + g*4 + r;
      #pragma unroll
      for (int nf = 0; nf < 2; ++nf) {
        int cc = col0 + nbase + nf*16 + col;
        float v = (acc[mf][nf][r] + biasv[nf]) * qs;
        C[(size_t)rr*384 + cc] = f2bf(v);
      }
    }
}

// Fused per-layer MLP block: attnout@Wo+bo+resq -> LN(ffn) -> relu(@W1+b1) -> @W2+b2+x
// -> mask -> (optional C=seqs_next) + LN(lnS2) -> lnOut. One block per 128 rows.
template<int WRITE_C>
__global__ __launch_bounds__(512) void mlp_kernel(
    const short* __restrict__ qkvQ, const short* __restrict__ resq,
    const short* __restrict__ wo_b, const float* __restrict__ bo,
    const float* __restrict__ ffnS, const float* __restrict__ ffnB,
    const short* __restrict__ w1_b, const float* __restrict__ b1,
    const short* __restrict__ w2_b, const float* __restrict__ b2,
    const int* __restrict__ lsq,
    short* __restrict__ C,
    const float* __restrict__ lnS2, const float* __restrict__ lnB2,
    short* __restrict__ lnOut){
  __shared__ short As[16384];
  __shared__ short Bs[16384];
  __shared__ float redP[2][4][128];
  __shared__ float muA[128], invA[128];
  char* AsB = (char*)As; char* BsB = (char*)Bs;
  const int row0 = blockIdx.x * 128;
  const int t = threadIdx.x;

  #pragma unroll
  for (int i = 0; i < 4; ++i) {
    int flat = t*8 + i*4096;
    int rr = flat >> 7, cc = flat & 127;
    bf16x8 a8 = *(const bf16x8*)(qkvQ + (size_t)(row0 + rr)*384 + cc);
    int byt = (rr*256 + cc*2) ^ ((rr & 7) << 4);
    *(bf16x8*)(AsB + byt) = a8;
    bf16x8 b8 = *(const bf16x8*)(wo_b + (size_t)rr*128 + cc);
    *(bf16x8*)(BsB + byt) = b8;
  }
  __syncthreads();

  const int w = t >> 6, l = t & 63;
  const int wm = w >> 2, wn = w & 3;
  const int col = l & 15, g = l >> 4;
  const int mbase = wm*64, nbase = wn*32;

  f32x4 acc[4][2];
  #pragma unroll
  for (int mf = 0; mf < 4; ++mf)
    #pragma unroll
    for (int nf = 0; nf < 2; ++nf) { f32x4 z = {0.f,0.f,0.f,0.f}; acc[mf][nf] = z; }
  MLP_MFMA(acc);

  float bov[2];
  #pragma unroll
  for (int nf = 0; nf < 2; ++nf) bov[nf] = bo[nbase + nf*16 + col];
  #pragma unroll
  for (int mf = 0; mf < 4; ++mf)
    #pragma unroll
    for (int r = 0; r < 4; ++r) {
      int rL = mbase + mf*16 + g*4 + r;
      #pragma unroll
      for (int nf = 0; nf < 2; ++nf) {
        int cL = nbase + nf*16 + col;
        acc[mf][nf][r] += bov[nf] + bf2f(((const unsigned short*)resq)[(size_t)(row0 + rL)*DIM + cL]);
      }
    }
  LN_REDUCE(acc);

  float xv[4][2][4];
  #pragma unroll
  for (int mf = 0; mf < 4; ++mf)
    #pragma unroll
    for (int r = 0; r < 4; ++r) {
      int rL = mbase + mf*16 + g*4 + r;
      float mu = muA[rL], inv = invA[rL];
      #pragma unroll
      for (int nf = 0; nf < 2; ++nf) {
        int cL = nbase + nf*16 + col;
        float lnv = (acc[mf][nf][r] - mu)*inv*ffnS[cL] + ffnB[cL];
        xv[mf][nf][r] = lnv;
        int byt = (rL*256 + cL*2) ^ ((rL & 7) << 4);
        *(short*)(AsB + byt) = f2bf(lnv);
      }
    }
  #pragma unroll
  for (int i = 0; i < 4; ++i) {
    int flat = t*8 + i*4096;
    int rr = flat >> 7, cc = flat & 127;
    bf16x8 b8 = *(const bf16x8*)(w1_b + (size_t)rr*128 + cc);
    int byt = (rr*256 + cc*2) ^ ((rr & 7) << 4);
    *(bf16x8*)(BsB + byt) = b8;
  }
  __syncthreads();

  #pragma unroll
  for (int mf = 0; mf < 4; ++mf)
    #pragma unroll
    for (int nf = 0; nf < 2; ++nf) { f32x4 z = {0.f,0.f,0.f,0.f}; acc[mf][nf] = z; }
  MLP_MFMA(acc);
  __syncthreads();

  float b1v[2];
  #pragma unroll
  for (int nf = 0; nf < 2; ++nf) b1v[nf] = b1[nbase + nf*16 + col];
  #pragma unroll
  for (int mf = 0; mf < 4; ++mf)
    #pragma unroll
    for (int r = 0; r < 4; ++r) {
      int rL = mbase + mf*16 + g*4 + r;
      #pragma unroll
      for (int nf = 0; nf < 2; ++nf) {
        int cL = nbase + nf*16 + col;
        float h = fmaxf(acc[mf][nf][r] + b1v[nf], 0.f);
        int byt = (rL*256 + cL*2) ^ ((rL & 7) << 4);
        *(short*)(AsB + byt) = f2bf(h);
      }
    }
  #pragma unroll
  for (int i = 0; i < 4; ++i) {
    int flat = t*8 + i*4096;
    int rr = flat >> 7, cc = flat & 127;
    bf16x8 b8 = *(const bf16x8*)(w2_b + (size_t)rr*128 + cc);
    int byt = (rr*256 + cc*2) ^ ((rr & 7) << 4);
    *(bf16x8*)(BsB + byt) = b8;
  }
  __syncthreads();

  #pragma unroll
  for (int mf = 0; mf < 4; ++mf)
    #pragma unroll
    for (int nf = 0; nf < 2; ++nf) { f32x4 z = {0.f,0.f,0.f,0.f}; acc[mf][nf] = z; }
  MLP_MFMA(acc);

  float b2v[2];
  #pragma unroll
  for (int nf = 0; nf < 2; ++nf) b2v[nf] = b2[nbase + nf*16 + col];
  #pragma unroll
  for (int mf = 0; mf < 4; ++mf)
    #pragma unroll
    for (int r = 0; r < 4; ++r) {
      int rL = mbase + mf*16 + g*4 + r;
      bool zr = (lsq[row0 + rL] == 0);
      #pragma unroll
      for (int nf = 0; nf < 2; ++nf) {
        float v = acc[mf][nf][r] + b2v[nf] + xv[mf][nf][r];
        if (zr) v = 0.f;
        acc[mf][nf][r] = v;
      }
    }
  LN_REDUCE(acc);
  #pragma unroll
  for (int mf = 0; mf < 4; ++mf)
    #pragma unroll
    for (int r = 0; r < 4; ++r) {
      int rL = mbase + mf*16 + g*4 + r;
      float mu = muA[rL], inv = invA[rL];
      #pragma unroll
      for (int nf = 0; nf < 2; ++nf) {
        int cL = nbase + nf*16 + col;
        float v = acc[mf][nf][r];
        float lnv = (v - mu)*inv*lnS2[cL] + lnB2[cL];
        lnOut[(size_t)(row0 + rL)*DIM + cL] = f2bf(lnv);
        if (WRITE_C) C[(size_t)(row0 + rL)*DIM + cL] = f2bf(v);
      }
    }
}

// MFMA causal attention, bf16 qkv, causal tile-skip. Out overwrites Q slot.
__global__ __launch_bounds__(512) void attn_kernel(short* __restrict__ qkv){
  __shared__ short Ks[224*64];
  __shared__ short Vt[64*224];
  __shared__ short Ps[8][16*232];
  const int b = blockIdx.x >> 1, h = blockIdx.x & 1;
  short* base = qkv + (size_t)b*L_SEQ*384 + h*64;
  const short* baseK = base + 128;
  const short* baseV = base + 256;
  const int t = threadIdx.x;
  char* KsB = (char*)Ks;
  char* VtB = (char*)Vt;

  for (int idx = t; idx < 224*8; idx += 512) {
    int row = idx >> 3, c8 = idx & 7;
    bf16x8 kv = {0,0,0,0,0,0,0,0}, vv = {0,0,0,0,0,0,0,0};
    if (row < L_SEQ) {
      kv = *(const bf16x8*)(baseK + (size_t)row*384 + c8*8);
      vv = *(const bf16x8*)(baseV + (size_t)row*384 + c8*8);
    }
    int kbyte = (row*128 + c8*16) ^ ((row & 7) << 4);
    *(bf16x8*)(KsB + kbyte) = kv;
    #pragma unroll
    for (int e = 0; e < 8; ++e) {
      int d = c8*8 + e;
      int vbyte = (d*448 + row*2) ^ ((d & 7) << 4);
      *(short*)(VtB + vbyte) = vv[e];
    }
  }
  __syncthreads();

  const int w = t >> 6, l = t & 63;
  const int col = l & 15, g = l >> 4, g4 = g * 4;
  char* PB = (char*)Ps[w];

  const int ntiles = (w < 5) ? 2 : 1;
  for (int j = 0; j < ntiles; ++j) {
    const int qt = w + 8*j;
    bf16x8 qf[2];
    {
      int gr = qt*16 + col;
      #pragma unroll
      for (int c = 0; c < 2; ++c) {
        bf16x8 q = {0,0,0,0,0,0,0,0};
        if (gr < L_SEQ) q = *(const bf16x8*)(base + (size_t)gr*384 + c*32 + g*8);
        qf[c] = q;
      }
    }
    f32x4 sc[13];
    #pragma unroll
    for (int kt = 0; kt < 13; ++kt) {
      if (kt <= qt) {
        f32x4 a = {0.f,0.f,0.f,0.f};
        #pragma unroll
        for (int c = 0; c < 2; ++c) {
          int row = kt*16 + col;
          int byt = (row*128 + c*64 + g*16) ^ ((row & 7) << 4);
          bf16x8 kf = *(bf16x8*)(KsB + byt);
          a = __builtin_amdgcn_mfma_f32_16x16x32_bf16(qf[c], kf, a, 0, 0, 0);
        }
        sc[kt] = a;
      }
    }
    float m[4] = {-1e30f,-1e30f,-1e30f,-1e30f};
    #pragma unroll
    for (int kt = 0; kt < 13; ++kt) {
      if (kt <= qt) {
        #pragma unroll
        for (int r = 0; r < 4; ++r) {
          bool ok = (kt < qt) || (col <= g4 + r);
          if (!ok) sc[kt][r] = -1e30f;
          m[r] = fmaxf(m[r], sc[kt][r]);
        }
      }
    }
    #pragma unroll
    for (int r = 0; r < 4; ++r) {
      #pragma unroll
      for (int o = 1; o <= 8; o <<= 1) m[r] = fmaxf(m[r], __shfl_xor(m[r], o));
    }
    float s[4] = {0.f,0.f,0.f,0.f};
    #pragma unroll
    for (int kt = 0; kt < 13; ++kt) {
      if (kt <= qt) {
        #pragma unroll
        for (int r = 0; r < 4; ++r) {
          float e = __expf(sc[kt][r] - m[r]);
          sc[kt][r] = e;
          s[r] += e;
        }
      }
    }
    float inv[4];
    #pragma unroll
    for (int r = 0; r < 4; ++r) {
      #pragma unroll
      for (int o = 1; o <= 8; o <<= 1) s[r] += __shfl_xor(s[r], o);
      inv[r] = 1.f / s[r];
    }
    #pragma unroll
    for (int kt = 0; kt < 13; ++kt) {
      if (kt <= qt) {
        #pragma unroll
        for (int r = 0; r < 4; ++r)
          *(short*)(PB + ((g4 + r)*232 + kt*16 + col)*2) = f2bf(sc[kt][r]);
      } else if (kt == qt + 1) {
        #pragma unroll
        for (int r = 0; r < 4; ++r)
          *(short*)(PB + ((g4 + r)*232 + kt*16 + col)*2) = 0;
      }
    }
    #pragma unroll
    for (int r = 0; r < 4; ++r)
      *(short*)(PB + ((g4 + r)*232 + 208 + col)*2) = 0;
    asm volatile("s_waitcnt lgkmcnt(0)" ::: "memory");
    f32x4 o4[4];
    #pragma unroll
    for (int nt = 0; nt < 4; ++nt) { f32x4 z = {0.f,0.f,0.f,0.f}; o4[nt] = z; }
    const int kcmax = (qt*16 + 15) >> 5;
    #pragma unroll
    for (int kc = 0; kc < 7; ++kc) {
      if (kc <= kcmax) {
        bf16x8 pf = *(bf16x8*)(PB + col*464 + kc*64 + g*16);
        #pragma unroll
        for (int nt = 0; nt < 4; ++nt) {
          int d = nt*16 + col;
          int byt = (d*448 + kc*64 + g*16) ^ ((d & 7) << 4);
          bf16x8 vf = *(bf16x8*)(VtB + byt);
          o4[nt] = __builtin_amdgcn_mfma_f32_16x16x32_bf16(pf, vf, o4[nt], 0, 0, 0);
        }
      }
    }
    #pragma unroll
    for (int nt = 0; nt < 4; ++nt)
      #pragma unroll
      for (int r = 0; r < 4; ++r) {
        int qr = qt*16 + g4 + r;
        if (qr < L_SEQ) base[(size_t)qr*384 + nt*16 + col] = f2bf(o4[nt][r] * inv[r]);
      }
  }
}

// out = feats + LN(nbr_agg + qn). 2 rows per wave: lanes 0-31 row A, 32-63 row B;
// each lane holds 4 dims (float4). 32-lane reductions (5 stages) serve both rows.
__global__ __launch_bounds__(256) void final_kernel(
    const short* __restrict__ feats_b, const int* __restrict__ lsq, const int* __restrict__ nbr,
    const float* __restrict__ item, const float* __restrict__ user,
    const float* __restrict__ is_, const float* __restrict__ ib,
    float* __restrict__ out){
  int wave = threadIdx.x >> 6, lane = threadIdx.x & 63;
  int half = lane >> 5, sl = lane & 31;
  size_t r = (size_t)blockIdx.x*8 + wave*2 + half;

  ushort4 fv = ((const ushort4*)(feats_b + r*DIM))[sl];
  float f0 = bf2f(fv.x), f1 = bf2f(fv.y), f2 = bf2f(fv.z), f3 = bf2f(fv.w);

  int it = lsq[r];
  float4 qv = ((const float4*)(item + (size_t)it*DIM))[sl];
  int idxs[10];
  #pragma unroll
  for (int n = 0; n < 10; ++n) idxs[n] = nbr[r*10 + n];
  float4 kn[10]; float scn[10];
  #pragma unroll
  for (int n = 0; n < 10; ++n) {
    kn[n] = ((const float4*)(user + (size_t)idxs[n]*DIM))[sl];
    float p = qv.x*kn[n].x + qv.y*kn[n].y + qv.z*kn[n].z + qv.w*kn[n].w;
    #pragma unroll
    for (int o = 1; o <= 16; o <<= 1) p += __shfl_xor(p, o);
    scn[n] = idxs[n] ? p * 0.08838834764831845f : -1.0e9f;
  }
  float m = scn[0];
  #pragma unroll
  for (int n = 1; n < 10; ++n) m = fmaxf(m, scn[n]);
  float w[10], sum = 0.f;
  #pragma unroll
  for (int n = 0; n < 10; ++n) { w[n] = expf(scn[n] - m); sum += w[n]; }
  float invs = 1.f / sum;
  float a0 = 0.f, a1 = 0.f, a2 = 0.f, a3 = 0.f;
  #pragma unroll
  for (int n = 0; n < 10; ++n) {
    a0 += w[n]*kn[n].x; a1 += w[n]*kn[n].y; a2 += w[n]*kn[n].z; a3 += w[n]*kn[n].w;
  }
  a0 = a0*invs + qv.x;
  a1 = a1*invs + qv.y;
  a2 = a2*invs + qv.z;
  a3 = a3*invs + qv.w;
  float s1 = a0 + a1 + a2 + a3;
  #pragma unroll
  for (int o = 1; o <= 16; o <<= 1) s1 += __shfl_xor(s1, o);
  float mu2 = s1 * (1.f/DIM);
  float d0 = a0 - mu2, d1 = a1 - mu2, d2 = a2 - mu2, d3 = a3 - mu2;
  float sq = d0*d0 + d1*d1 + d2*d2 + d3*d3;
  #pragma unroll
  for (int o = 1; o <= 16; o <<= 1) sq += __shfl_xor(sq, o);
  float inv2 = 1.f / sqrtf(sq * (1.f/DIM) + 1e-8f);
  float4 isc = ((const float4*)is_)[sl], ibc = ((const float4*)ib)[sl];
  float4 o;
  o.x = f0 + d0*inv2*isc.x + ibc.x;
  o.y = f1 + d1*inv2*isc.y + ibc.y;
  o.z = f2 + d2*inv2*isc.z + ibc.z;
  o.w = f3 + d3*inv2*isc.w + ibc.w;
  ((float4*)(out + r*DIM))[sl] = o;
}

extern "C" void kernel_launch(void* const* d_in, const int* in_sizes, int n_in,
                              void* d_out, int out_size, void* d_ws, size_t ws_size,
                              hipStream_t stream) {
  const int*   lsq    = (const int*)d_in[0];
  const int*   nbr    = (const int*)d_in[1];
  const float* item   = (const float*)d_in[2];
  const float* user   = (const float*)d_in[3];
  const float* pos    = (const float*)d_in[4];
  const float* attn_s = (const float*)d_in[5];
  const float* attn_b = (const float*)d_in[6];
  const float* Wqkv   = (const float*)d_in[7];
  const float* bqkv   = (const float*)d_in[8];
  const float* Wo     = (const float*)d_in[9];
  const float* bo     = (const float*)d_in[10];
  const float* ffn_s  = (const float*)d_in[11];
  const float* ffn_b  = (const float*)d_in[12];
  const float* W1     = (const float*)d_in[13];
  const float* b1     = (const float*)d_in[14];
  const float* W2     = (const float*)d_in[15];
  const float* b2     = (const float*)d_in[16];
  const float* last_s = (const float*)d_in[17];
  const float* last_b = (const float*)d_in[18];
  const float* iui_s  = (const float*)d_in[19];
  const float* iui_b  = (const float*)d_in[20];
  float* out = (float*)d_out;

  const int N = NROWS;  // 51200 rows
  short* seqs_b = (short*)d_ws;                       // N x 128 bf16
  short* lnq_b  = seqs_b + (size_t)N*DIM;             // N x 128 bf16
  short* qkv_b  = lnq_b  + (size_t)N*DIM;             // N x 384 bf16
  short* wqkv_b = qkv_b  + (size_t)N*384;             // 2 x 384 x 128
  short* wo_b   = wqkv_b + 2*384*128;
  short* w1_b   = wo_b   + 2*128*128;
  short* w2_b   = w1_b   + 2*128*128;

  cvt_all_kernel<<<192, 256, 0, stream>>>(Wqkv, Wo, W1, W2, wqkv_b);

  embed_ln_kernel<<<N/4, 256, 0, stream>>>(lsq, item, pos, attn_s, attn_b, seqs_b, lnq_b);

  for (int i = 0; i < 2; ++i) {
    qkv_kernel<<<dim3(3, N/128), 512, 0, stream>>>(
        lnq_b, seqs_b, wqkv_b + (size_t)i*384*128, bqkv + i*384, qkv_b);
    attn_kernel<<<256*2, 512, 0, stream>>>(qkv_b);
    if (i == 0) {
      mlp_kernel<1><<<N/128, 512, 0, stream>>>(
          qkv_b, lnq_b, wo_b, bo, ffn_s, ffn_b,
          w1_b, b1, w2_b, b2, lsq,
          seqs_b, attn_s + DIM, attn_b + DIM, lnq_b);
    } else {
      mlp_kernel<0><<<N/128, 512, 0, stream>>>(
          qkv_b, lnq_b, wo_b + 128*128, bo + DIM, ffn_s + DIM, ffn_b + DIM,
          w1_b + 128*128, b1 + DIM, w2_b + 128*128, b2 + DIM, lsq,
          nullptr, last_s, last_b, lnq_b);
    }
  }

  final_kernel<<<N/8, 256, 0, stream>>>(lnq_b, lsq, nbr, item, user,
                                        iui_s, iui_b, out);
}

// Round 8
// 210.979 us; speedup vs baseline: 5.8378x; 1.0583x over previous
//
#include <hip/hip_runtime.h>
#include <hip/hip_bf16.h>

#define L_SEQ 200
#define DIM 128
#define NROWS (256*200)

typedef __attribute__((ext_vector_type(8))) short bf16x8;
typedef __attribute__((ext_vector_type(4))) float f32x4;

__device__ __forceinline__ float wave_sum(float v){
  #pragma unroll
  for (int o = 32; o; o >>= 1) v += __shfl_xor(v, o);
  return v;
}
__device__ __forceinline__ short f2bf(float f){
  union { float f; unsigned u; } x; x.f = f;
  unsigned r = x.u + 0x7fffu + ((x.u >> 16) & 1u);
  return (short)(r >> 16);
}
__device__ __forceinline__ float bf2f(unsigned short u){
  union { unsigned u; float f; } x; x.u = ((unsigned)u) << 16;
  return x.f;
}

// all four bf16 weight arrays in one launch (dst arrays are contiguous)
__global__ void cvt_all_kernel(const float* __restrict__ Wqkv, const float* __restrict__ Wo,
                               const float* __restrict__ W1, const float* __restrict__ W2,
                               short* __restrict__ dst){
  int i = blockIdx.x*256 + threadIdx.x;   // float4 index, total 49152
  if (i >= 49152) return;
  const float* src; int off;
  if (i < 24576)      { src = Wqkv; off = i; }
  else if (i < 32768) { src = Wo;   off = i - 24576; }
  else if (i < 40960) { src = W1;   off = i - 32768; }
  else                { src = W2;   off = i - 40960; }
  float4 v = ((const float4*)src)[off];
  short4 s; s.x = f2bf(v.x); s.y = f2bf(v.y); s.z = f2bf(v.z); s.w = f2bf(v.w);
  ((short4*)dst)[i] = s;
}

// generic fp32 -> bf16 (user table)
__global__ void cvt4_kernel(const float* __restrict__ src, short* __restrict__ dst, int n4){
  int i = blockIdx.x*256 + threadIdx.x;
  if (i < n4) {
    float4 v = ((const float4*)src)[i];
    short4 s; s.x = f2bf(v.x); s.y = f2bf(v.y); s.z = f2bf(v.z); s.w = f2bf(v.w);
    ((short4*)dst)[i] = s;
  }
}

// seqs = item[log_seqs]*sqrt(D)+pos (masked); lnq = LN(seqs, attn_ln0);
// qn_b = bf16(item[log_seqs]) stash for final. bf16 out.
__global__ __launch_bounds__(256) void embed_ln_kernel(
    const int* __restrict__ lsq, const float* __restrict__ item,
    const float* __restrict__ pos, const float* __restrict__ s, const float* __restrict__ b,
    short* __restrict__ seqs_b, short* __restrict__ lnq_b, short* __restrict__ qn_b){
  int wave = threadIdx.x >> 6, lane = threadIdx.x & 63;
  size_t r = (size_t)blockIdx.x*4 + wave;
  int it = lsq[r];
  float2 iv = ((const float2*)(item + (size_t)it*DIM))[lane];
  float2 p = ((const float2*)(pos + (r % L_SEQ)*DIM))[lane];
  short2 qv; qv.x = f2bf(iv.x); qv.y = f2bf(iv.y);
  ((short2*)(qn_b + r*DIM))[lane] = qv;
  float vx = 0.f, vy = 0.f;
  if (it) {
    vx = iv.x * 11.313708498984761f + p.x;
    vy = iv.y * 11.313708498984761f + p.y;
  }
  short2 sv; sv.x = f2bf(vx); sv.y = f2bf(vy);
  ((short2*)(seqs_b + r*DIM))[lane] = sv;
  float mu = wave_sum(vx + vy) * (1.f/DIM);
  float dx = vx - mu, dy = vy - mu;
  float var = wave_sum(dx*dx + dy*dy) * (1.f/DIM);
  float inv = 1.f / sqrtf(var + 1e-8f);
  float2 sc = ((const float2*)s)[lane];
  float2 bc = ((const float2*)b)[lane];
  short2 ov; ov.x = f2bf(dx*inv*sc.x + bc.x); ov.y = f2bf(dy*inv*sc.y + bc.y);
  ((short2*)(lnq_b + r*DIM))[lane] = ov;
}

#define MLP_MFMA(accv) do { \
  _Pragma("unroll") \
  for (int kc = 0; kc < 4; ++kc) { \
    bf16x8 af[4], bfr[2]; \
    _Pragma("unroll") \
    for (int mf = 0; mf < 4; ++mf) { \
      int rr = mbase + mf*16 + col; \
      int byt = (rr*256 + kc*64 + g*16) ^ ((rr & 7) << 4); \
      af[mf] = *(bf16x8*)(AsB + byt); \
    } \
    _Pragma("unroll") \
    for (int nf = 0; nf < 2; ++nf) { \
      int rr = nbase + nf*16 + col; \
      int byt = (rr*256 + kc*64 + g*16) ^ ((rr & 7) << 4); \
      bfr[nf] = *(bf16x8*)(BsB + byt); \
    } \
    _Pragma("unroll") \
    for (int mf = 0; mf < 4; ++mf) \
      _Pragma("unroll") \
      for (int nf = 0; nf < 2; ++nf) \
        accv[mf][nf] = __builtin_amdgcn_mfma_f32_16x16x32_bf16(af[mf], bfr[nf], accv[mf][nf], 0, 0, 0); \
  } \
} while(0)

#define LN_REDUCE(accv) do { \
  _Pragma("unroll") \
  for (int mf = 0; mf < 4; ++mf) { \
    _Pragma("unroll") \
    for (int r = 0; r < 4; ++r) { \
      float s1 = accv[mf][0][r] + accv[mf][1][r]; \
      float s2 = accv[mf][0][r]*accv[mf][0][r] + accv[mf][1][r]*accv[mf][1][r]; \
      _Pragma("unroll") \
      for (int o = 1; o <= 8; o <<= 1) { s1 += __shfl_xor(s1, o); s2 += __shfl_xor(s2, o); } \
      if (col == 0) { int rL = mbase + mf*16 + g*4 + r; redP[0][wn][rL] = s1; redP[1][wn][rL] = s2; } \
    } \
  } \
  __syncthreads(); \
  if (t < 128) { \
    float s1 = redP[0][0][t] + redP[0][1][t] + redP[0][2][t] + redP[0][3][t]; \
    float s2 = redP[1][0][t] + redP[1][1][t] + redP[1][2][t] + redP[1][3][t]; \
    float mu_ = s1 * (1.f/DIM); \
    float var_ = s2 * (1.f/DIM) - mu_*mu_; \
    muA[t] = mu_; invA[t] = 1.f / sqrtf(var_ + 1e-8f); \
  } \
  __syncthreads(); \
} while(0)

// QKV projection: grid (3, N/128). x==0 -> Q from lnq (scaled 1/8), x=1,2 -> K,V from seqs.
__global__ __launch_bounds__(512) void qkv_kernel(
    const short* __restrict__ lnq, const short* __restrict__ seqs,
    const short* __restrict__ Wb, const float* __restrict__ bias,
    short* __restrict__ C){
  __shared__ short As[16384];
  __shared__ short Bs[16384];
  char* AsB = (char*)As; char* BsB = (char*)Bs;
  const int row0 = blockIdx.y * 128, col0 = blockIdx.x * 128;
  const int t = threadIdx.x;
  const short* Ap = (blockIdx.x == 0) ? lnq : seqs;

  #pragma unroll
  for (int i = 0; i < 4; ++i) {
    int flat = t*8 + i*4096;
    int rr = flat >> 7, cc = flat & 127;
    bf16x8 a8 = *(const bf16x8*)(Ap + (size_t)(row0 + rr)*128 + cc);
    int byt = (rr*256 + cc*2) ^ ((rr & 7) << 4);
    *(bf16x8*)(AsB + byt) = a8;
    bf16x8 b8 = *(const bf16x8*)(Wb + (size_t)(col0 + rr)*128 + cc);
    *(bf16x8*)(BsB + byt) = b8;
  }
  __syncthreads();

  const int w = t >> 6, l = t & 63;
  const int wm = w >> 2, wn = w & 3;
  const int col = l & 15, g = l >> 4;
  const int mbase = wm*64, nbase = wn*32;

  f32x4 acc[4][2];
  #pragma unroll
  for (int mf = 0; mf < 4; ++mf)
    #pragma unroll
    for (int nf = 0; nf < 2; ++nf) { f32x4 z = {0.f,0.f,0.f,0.f}; acc[mf][nf] = z; }
  MLP_MFMA(acc);

  float biasv[2];
  #pragma unroll
  for (int nf = 0; nf < 2; ++nf) biasv[nf] = bias[col0 + nbase + nf*16 + col];
  const float qs = (blockIdx.x == 0) ? 0.125f : 1.f;
  #pragma unroll
  for (int mf = 0; mf < 4; ++mf)
    #pragma unroll
    for (int r = 0; r < 4; ++r) {
      int rr = row0 + mbase + mf*16 + g*4 + r;
      #pragma unroll
      for (int nf = 0; nf < 2; ++nf) {
        int cc = col0 + nbase + nf*16 + col;
        float v = (acc[mf][nf][r] + biasv[nf]) * qs;
        C[(size_t)rr*384 + cc] = f2bf(v);
      }
    }
}

// Fused per-layer MLP block: attnout@Wo+bo+resq -> LN(ffn) -> relu(@W1+b1) -> @W2+b2+x
// -> mask -> (optional C=seqs_next) + LN(lnS2) -> lnOut. One block per 128 rows.
template<int WRITE_C>
__global__ __launch_bounds__(512) void mlp_kernel(
    const short* __restrict__ qkvQ, const short* __restrict__ resq,
    const short* __restrict__ wo_b, const float* __restrict__ bo,
    const float* __restrict__ ffnS, const float* __restrict__ ffnB,
    const short* __restrict__ w1_b, const float* __restrict__ b1,
    const short* __restrict__ w2_b, const float* __restrict__ b2,
    const int* __restrict__ lsq,
    short* __restrict__ C,
    const float* __restrict__ lnS2, const float* __restrict__ lnB2,
    short* __restrict__ lnOut){
  __shared__ short As[16384];
  __shared__ short Bs[16384];
  __shared__ float redP[2][4][128];
  __shared__ float muA[128], invA[128];
  char* AsB = (char*)As; char* BsB = (char*)Bs;
  const int row0 = blockIdx.x * 128;
  const int t = threadIdx.x;

  #pragma unroll
  for (int i = 0; i < 4; ++i) {
    int flat = t*8 + i*4096;
    int rr = flat >> 7, cc = flat & 127;
    bf16x8 a8 = *(const bf16x8*)(qkvQ + (size_t)(row0 + rr)*384 + cc);
    int byt = (rr*256 + cc*2) ^ ((rr & 7) << 4);
    *(bf16x8*)(AsB + byt) = a8;
    bf16x8 b8 = *(const bf16x8*)(wo_b + (size_t)rr*128 + cc);
    *(bf16x8*)(BsB + byt) = b8;
  }
  __syncthreads();

  const int w = t >> 6, l = t & 63;
  const int wm = w >> 2, wn = w & 3;
  const int col = l & 15, g = l >> 4;
  const int mbase = wm*64, nbase = wn*32;

  f32x4 acc[4][2];
  #pragma unroll
  for (int mf = 0; mf < 4; ++mf)
    #pragma unroll
    for (int nf = 0; nf < 2; ++nf) { f32x4 z = {0.f,0.f,0.f,0.f}; acc[mf][nf] = z; }
  MLP_MFMA(acc);

  float bov[2];
  #pragma unroll
  for (int nf = 0; nf < 2; ++nf) bov[nf] = bo[nbase + nf*16 + col];
  #pragma unroll
  for (int mf = 0; mf < 4; ++mf)
    #pragma unroll
    for (int r = 0; r < 4; ++r) {
      int rL = mbase + mf*16 + g*4 + r;
      #pragma unroll
      for (int nf = 0; nf < 2; ++nf) {
        int cL = nbase + nf*16 + col;
        acc[mf][nf][r] += bov[nf] + bf2f(((const unsigned short*)resq)[(size_t)(row0 + rL)*DIM + cL]);
      }
    }
  LN_REDUCE(acc);

  float xv[4][2][4];
  #pragma unroll
  for (int mf = 0; mf < 4; ++mf)
    #pragma unroll
    for (int r = 0; r < 4; ++r) {
      int rL = mbase + mf*16 + g*4 + r;
      float mu = muA[rL], inv = invA[rL];
      #pragma unroll
      for (int nf = 0; nf < 2; ++nf) {
        int cL = nbase + nf*16 + col;
        float lnv = (acc[mf][nf][r] - mu)*inv*ffnS[cL] + ffnB[cL];
        xv[mf][nf][r] = lnv;
        int byt = (rL*256 + cL*2) ^ ((rL & 7) << 4);
        *(short*)(AsB + byt) = f2bf(lnv);
      }
    }
  #pragma unroll
  for (int i = 0; i < 4; ++i) {
    int flat = t*8 + i*4096;
    int rr = flat >> 7, cc = flat & 127;
    bf16x8 b8 = *(const bf16x8*)(w1_b + (size_t)rr*128 + cc);
    int byt = (rr*256 + cc*2) ^ ((rr & 7) << 4);
    *(bf16x8*)(BsB + byt) = b8;
  }
  __syncthreads();

  #pragma unroll
  for (int mf = 0; mf < 4; ++mf)
    #pragma unroll
    for (int nf = 0; nf < 2; ++nf) { f32x4 z = {0.f,0.f,0.f,0.f}; acc[mf][nf] = z; }
  MLP_MFMA(acc);
  __syncthreads();

  float b1v[2];
  #pragma unroll
  for (int nf = 0; nf < 2; ++nf) b1v[nf] = b1[nbase + nf*16 + col];
  #pragma unroll
  for (int mf = 0; mf < 4; ++mf)
    #pragma unroll
    for (int r = 0; r < 4; ++r) {
      int rL = mbase + mf*16 + g*4 + r;
      #pragma unroll
      for (int nf = 0; nf < 2; ++nf) {
        int cL = nbase + nf*16 + col;
        float h = fmaxf(acc[mf][nf][r] + b1v[nf], 0.f);
        int byt = (rL*256 + cL*2) ^ ((rL & 7) << 4);
        *(short*)(AsB + byt) = f2bf(h);
      }
    }
  #pragma unroll
  for (int i = 0; i < 4; ++i) {
    int flat = t*8 + i*4096;
    int rr = flat >> 7, cc = flat & 127;
    bf16x8 b8 = *(const bf16x8*)(w2_b + (size_t)rr*128 + cc);
    int byt = (rr*256 + cc*2) ^ ((rr & 7) << 4);
    *(bf16x8*)(BsB + byt) = b8;
  }
  __syncthreads();

  #pragma unroll
  for (int mf = 0; mf < 4; ++mf)
    #pragma unroll
    for (int nf = 0; nf < 2; ++nf) { f32x4 z = {0.f,0.f,0.f,0.f}; acc[mf][nf] = z; }
  MLP_MFMA(acc);

  float b2v[2];
  #pragma unroll
  for (int nf = 0; nf < 2; ++nf) b2v[nf] = b2[nbase + nf*16 + col];
  #pragma unroll
  for (int mf = 0; mf < 4; ++mf)
    #pragma unroll
    for (int r = 0; r < 4; ++r) {
      int rL = mbase + mf*16 + g*4 + r;
      bool zr = (lsq[row0 + rL] == 0);
      #pragma unroll
      for (int nf = 0; nf < 2; ++nf) {
        float v = acc[mf][nf][r] + b2v[nf] + xv[mf][nf][r];
        if (zr) v = 0.f;
        acc[mf][nf][r] = v;
      }
    }
  LN_REDUCE(acc);
  #pragma unroll
  for (int mf = 0; mf < 4; ++mf)
    #pragma unroll
    for (int r = 0; r < 4; ++r) {
      int rL = mbase + mf*16 + g*4 + r;
      float mu = muA[rL], inv = invA[rL];
      #pragma unroll
      for (int nf = 0; nf < 2; ++nf) {
        int cL = nbase + nf*16 + col;
        float v = acc[mf][nf][r];
        float lnv = (v - mu)*inv*lnS2[cL] + lnB2[cL];
        lnOut[(size_t)(row0 + rL)*DIM + cL] = f2bf(lnv);
        if (WRITE_C) C[(size_t)(row0 + rL)*DIM + cL] = f2bf(v);
      }
    }
}

// MFMA causal attention, bf16 qkv, causal tile-skip + balanced wave->qtile pairing.
__global__ __launch_bounds__(512) void attn_kernel(short* __restrict__ qkv){
  __shared__ short Ks[224*64];
  __shared__ short Vt[64*224];
  __shared__ short Ps[8][16*232];
  const int b = blockIdx.x >> 1, h = blockIdx.x & 1;
  short* base = qkv + (size_t)b*L_SEQ*384 + h*64;
  const short* baseK = base + 128;
  const short* baseV = base + 256;
  const int t = threadIdx.x;
  char* KsB = (char*)Ks;
  char* VtB = (char*)Vt;

  for (int idx = t; idx < 224*8; idx += 512) {
    int row = idx >> 3, c8 = idx & 7;
    bf16x8 kv = {0,0,0,0,0,0,0,0}, vv = {0,0,0,0,0,0,0,0};
    if (row < L_SEQ) {
      kv = *(const bf16x8*)(baseK + (size_t)row*384 + c8*8);
      vv = *(const bf16x8*)(baseV + (size_t)row*384 + c8*8);
    }
    int kbyte = (row*128 + c8*16) ^ ((row & 7) << 4);
    *(bf16x8*)(KsB + kbyte) = kv;
    #pragma unroll
    for (int e = 0; e < 8; ++e) {
      int d = c8*8 + e;
      int vbyte = (d*448 + row*2) ^ ((d & 7) << 4);
      *(short*)(VtB + vbyte) = vv[e];
    }
  }
  __syncthreads();

  const int w = t >> 6, l = t & 63;
  const int col = l & 15, g = l >> 4, g4 = g * 4;
  char* PB = (char*)Ps[w];

  // balanced pairing: wave w<5 handles {w, 12-w}; waves 5,6,7 handle {5},{6},{7}
  const int ntiles = (w < 5) ? 2 : 1;
  for (int j = 0; j < ntiles; ++j) {
    const int qt = (j == 0) ? w : 12 - w;
    bf16x8 qf[2];
    {
      int gr = qt*16 + col;
      #pragma unroll
      for (int c = 0; c < 2; ++c) {
        bf16x8 q = {0,0,0,0,0,0,0,0};
        if (gr < L_SEQ) q = *(const bf16x8*)(base + (size_t)gr*384 + c*32 + g*8);
        qf[c] = q;
      }
    }
    f32x4 sc[13];
    #pragma unroll
    for (int kt = 0; kt < 13; ++kt) {
      if (kt <= qt) {
        f32x4 a = {0.f,0.f,0.f,0.f};
        #pragma unroll
        for (int c = 0; c < 2; ++c) {
          int row = kt*16 + col;
          int byt = (row*128 + c*64 + g*16) ^ ((row & 7) << 4);
          bf16x8 kf = *(bf16x8*)(KsB + byt);
          a = __builtin_amdgcn_mfma_f32_16x16x32_bf16(qf[c], kf, a, 0, 0, 0);
        }
        sc[kt] = a;
      }
    }
    float m[4] = {-1e30f,-1e30f,-1e30f,-1e30f};
    #pragma unroll
    for (int kt = 0; kt < 13; ++kt) {
      if (kt <= qt) {
        #pragma unroll
        for (int r = 0; r < 4; ++r) {
          bool ok = (kt < qt) || (col <= g4 + r);
          if (!ok) sc[kt][r] = -1e30f;
          m[r] = fmaxf(m[r], sc[kt][r]);
        }
      }
    }
    #pragma unroll
    for (int r = 0; r < 4; ++r) {
      #pragma unroll
      for (int o = 1; o <= 8; o <<= 1) m[r] = fmaxf(m[r], __shfl_xor(m[r], o));
    }
    float s[4] = {0.f,0.f,0.f,0.f};
    #pragma unroll
    for (int kt = 0; kt < 13; ++kt) {
      if (kt <= qt) {
        #pragma unroll
        for (int r = 0; r < 4; ++r) {
          float e = __expf(sc[kt][r] - m[r]);
          sc[kt][r] = e;
          s[r] += e;
        }
      }
    }
    float inv[4];
    #pragma unroll
    for (int r = 0; r < 4; ++r) {
      #pragma unroll
      for (int o = 1; o <= 8; o <<= 1) s[r] += __shfl_xor(s[r], o);
      inv[r] = 1.f / s[r];
    }
    #pragma unroll
    for (int kt = 0; kt < 13; ++kt) {
      if (kt <= qt) {
        #pragma unroll
        for (int r = 0; r < 4; ++r)
          *(short*)(PB + ((g4 + r)*232 + kt*16 + col)*2) = f2bf(sc[kt][r]);
      } else if (kt == qt + 1) {
        #pragma unroll
        for (int r = 0; r < 4; ++r)
          *(short*)(PB + ((g4 + r)*232 + kt*16 + col)*2) = 0;
      }
    }
    #pragma unroll
    for (int r = 0; r < 4; ++r)
      *(short*)(PB + ((g4 + r)*232 + 208 + col)*2) = 0;
    asm volatile("s_waitcnt lgkmcnt(0)" ::: "memory");
    f32x4 o4[4];
    #pragma unroll
    for (int nt = 0; nt < 4; ++nt) { f32x4 z = {0.f,0.f,0.f,0.f}; o4[nt] = z; }
    const int kcmax = (qt*16 + 15) >> 5;
    #pragma unroll
    for (int kc = 0; kc < 7; ++kc) {
      if (kc <= kcmax) {
        bf16x8 pf = *(bf16x8*)(PB + col*464 + kc*64 + g*16);
        #pragma unroll
        for (int nt = 0; nt < 4; ++nt) {
          int d = nt*16 + col;
          int byt = (d*448 + kc*64 + g*16) ^ ((d & 7) << 4);
          bf16x8 vf = *(bf16x8*)(VtB + byt);
          o4[nt] = __builtin_amdgcn_mfma_f32_16x16x32_bf16(pf, vf, o4[nt], 0, 0, 0);
        }
      }
    }
    #pragma unroll
    for (int nt = 0; nt < 4; ++nt)
      #pragma unroll
      for (int r = 0; r < 4; ++r) {
        int qr = qt*16 + g4 + r;
        if (qr < L_SEQ) base[(size_t)qr*384 + nt*16 + col] = f2bf(o4[nt][r] * inv[r]);
      }
  }
}

// out = feats + LN(nbr_agg + qn). 2 rows per wave; qn from bf16 stash (sequential),
// user gathers from bf16 table (256B rows, 8B/lane).
__global__ __launch_bounds__(256) void final_kernel(
    const short* __restrict__ feats_b, const short* __restrict__ qn_b,
    const int* __restrict__ nbr, const short* __restrict__ user_b,
    const float* __restrict__ is_, const float* __restrict__ ib,
    float* __restrict__ out){
  int wave = threadIdx.x >> 6, lane = threadIdx.x & 63;
  int half = lane >> 5, sl = lane & 31;
  size_t r = (size_t)blockIdx.x*8 + wave*2 + half;

  ushort4 fv = ((const ushort4*)(feats_b + r*DIM))[sl];
  float f0 = bf2f(fv.x), f1 = bf2f(fv.y), f2 = bf2f(fv.z), f3 = bf2f(fv.w);
  ushort4 qv4 = ((const ushort4*)(qn_b + r*DIM))[sl];
  float q0 = bf2f(qv4.x), q1 = bf2f(qv4.y), q2 = bf2f(qv4.z), q3 = bf2f(qv4.w);

  int idxs[10];
  #pragma unroll
  for (int n = 0; n < 10; ++n) idxs[n] = nbr[r*10 + n];
  float kn[10][4]; float scn[10];
  #pragma unroll
  for (int n = 0; n < 10; ++n) {
    ushort4 kv = ((const ushort4*)(user_b + (size_t)idxs[n]*DIM))[sl];
    kn[n][0] = bf2f(kv.x); kn[n][1] = bf2f(kv.y); kn[n][2] = bf2f(kv.z); kn[n][3] = bf2f(kv.w);
    float p = q0*kn[n][0] + q1*kn[n][1] + q2*kn[n][2] + q3*kn[n][3];
    #pragma unroll
    for (int o = 1; o <= 16; o <<= 1) p += __shfl_xor(p, o);
    scn[n] = idxs[n] ? p * 0.08838834764831845f : -1.0e9f;
  }
  float m = scn[0];
  #pragma unroll
  for (int n = 1; n < 10; ++n) m = fmaxf(m, scn[n]);
  float w[10], sum = 0.f;
  #pragma unroll
  for (int n = 0; n < 10; ++n) { w[n] = expf(scn[n] - m); sum += w[n]; }
  float invs = 1.f / sum;
  float a0 = 0.f, a1 = 0.f, a2 = 0.f, a3 = 0.f;
  #pragma unroll
  for (int n = 0; n < 10; ++n) {
    a0 += w[n]*kn[n][0]; a1 += w[n]*kn[n][1]; a2 += w[n]*kn[n][2]; a3 += w[n]*kn[n][3];
  }
  a0 = a0*invs + q0;
  a1 = a1*invs + q1;
  a2 = a2*invs + q2;
  a3 = a3*invs + q3;
  float s1 = a0 + a1 + a2 + a3;
  #pragma unroll
  for (int o = 1; o <= 16; o <<= 1) s1 += __shfl_xor(s1, o);
  float mu2 = s1 * (1.f/DIM);
  float d0 = a0 - mu2, d1 = a1 - mu2, d2 = a2 - mu2, d3 = a3 - mu2;
  float sq = d0*d0 + d1*d1 + d2*d2 + d3*d3;
  #pragma unroll
  for (int o = 1; o <= 16; o <<= 1) sq += __shfl_xor(sq, o);
  float inv2 = 1.f / sqrtf(sq * (1.f/DIM) + 1e-8f);
  float4 isc = ((const float4*)is_)[sl], ibc = ((const float4*)ib)[sl];
  float4 o;
  o.x = f0 + d0*inv2*isc.x + ibc.x;
  o.y = f1 + d1*inv2*isc.y + ibc.y;
  o.z = f2 + d2*inv2*isc.z + ibc.z;
  o.w = f3 + d3*inv2*isc.w + ibc.w;
  ((float4*)(out + r*DIM))[sl] = o;
}

extern "C" void kernel_launch(void* const* d_in, const int* in_sizes, int n_in,
                              void* d_out, int out_size, void* d_ws, size_t ws_size,
                              hipStream_t stream) {
  const int*   lsq    = (const int*)d_in[0];
  const int*   nbr    = (const int*)d_in[1];
  const float* item   = (const float*)d_in[2];
  const float* user   = (const float*)d_in[3];
  const float* pos    = (const float*)d_in[4];
  const float* attn_s = (const float*)d_in[5];
  const float* attn_b = (const float*)d_in[6];
  const float* Wqkv   = (const float*)d_in[7];
  const float* bqkv   = (const float*)d_in[8];
  const float* Wo     = (const float*)d_in[9];
  const float* bo     = (const float*)d_in[10];
  const float* ffn_s  = (const float*)d_in[11];
  const float* ffn_b  = (const float*)d_in[12];
  const float* W1     = (const float*)d_in[13];
  const float* b1     = (const float*)d_in[14];
  const float* W2     = (const float*)d_in[15];
  const float* b2     = (const float*)d_in[16];
  const float* last_s = (const float*)d_in[17];
  const float* last_b = (const float*)d_in[18];
  const float* iui_s  = (const float*)d_in[19];
  const float* iui_b  = (const float*)d_in[20];
  float* out = (float*)d_out;

  const int N = NROWS;  // 51200 rows
  short* seqs_b = (short*)d_ws;                       // N x 128 bf16
  short* lnq_b  = seqs_b + (size_t)N*DIM;             // N x 128 bf16
  short* qkv_b  = lnq_b  + (size_t)N*DIM;             // N x 384 bf16
  short* wqkv_b = qkv_b  + (size_t)N*384;             // 2 x 384 x 128
  short* wo_b   = wqkv_b + 2*384*128;
  short* w1_b   = wo_b   + 2*128*128;
  short* w2_b   = w1_b   + 2*128*128;
  short* user_b = w2_b   + 2*128*128;                 // 50001 x 128 bf16
  short* qn_b   = user_b + (size_t)50001*DIM + 64;    // N x 128 bf16

  cvt_all_kernel<<<192, 256, 0, stream>>>(Wqkv, Wo, W1, W2, wqkv_b);
  cvt4_kernel<<<(50001*DIM/4 + 255)/256, 256, 0, stream>>>(user, user_b, 50001*DIM/4);

  embed_ln_kernel<<<N/4, 256, 0, stream>>>(lsq, item, pos, attn_s, attn_b,
                                           seqs_b, lnq_b, qn_b);

  for (int i = 0; i < 2; ++i) {
    qkv_kernel<<<dim3(3, N/128), 512, 0, stream>>>(
        lnq_b, seqs_b, wqkv_b + (size_t)i*384*128, bqkv + i*384, qkv_b);
    attn_kernel<<<256*2, 512, 0, stream>>>(qkv_b);
    if (i == 0) {
      mlp_kernel<1><<<N/128, 512, 0, stream>>>(
          qkv_b, lnq_b, wo_b, bo, ffn_s, ffn_b,
          w1_b, b1, w2_b, b2, lsq,
          seqs_b, attn_s + DIM, attn_b + DIM, lnq_b);
    } else {
      mlp_kernel<0><<<N/128, 512, 0, stream>>>(
          qkv_b, lnq_b, wo_b + 128*128, bo + DIM, ffn_s + DIM, ffn_b + DIM,
          w1_b + 128*128, b1 + DIM, w2_b + 128*128, b2 + DIM, lsq,
          nullptr, last_s, last_b, lnq_b);
    }
  }

  final_kernel<<<N/8, 256, 0, stream>>>(lnq_b, qn_b, nbr, user_b,
                                        iui_s, iui_b, out);
}